// Round 1
// baseline (585.839 us; speedup 1.0000x reference)
//
#include <hip/hip_runtime.h>

#define TN 32

// ---------------------------------------------------------------------------
// Kernel A: per-image LeNet conv stage. 1 block = 1 image, 256 threads.
// conv1(pad2)+relu+pool fused at pooled granularity; conv2+relu+pool fused as
// 2x2 output quads (quad == pool window). Writes h[N,400].
// ---------------------------------------------------------------------------
__global__ __launch_bounds__(256) void lenet_conv(
    const float* __restrict__ x,
    const float* __restrict__ c1w, const float* __restrict__ c1b,
    const float* __restrict__ c2w, const float* __restrict__ c2b,
    float* __restrict__ hout, int N)
{
    __shared__ float img[32 * 32];   // zero-padded 28x28 -> 32x32
    __shared__ float w1s[150];
    __shared__ float b1s[6];
    __shared__ float w2s[2400];
    __shared__ float b2s[16];
    __shared__ float p1[6 * 196];    // pooled conv1 output [6][14][14]

    const int tid = threadIdx.x;
    const int n = blockIdx.x;
    const float* __restrict__ xi = x + (size_t)n * 784;

    for (int i = tid; i < 1024; i += 256) img[i] = 0.f;
    for (int i = tid; i < 150; i += 256) w1s[i] = c1w[i];
    for (int i = tid; i < 2400; i += 256) w2s[i] = c2w[i];
    if (tid < 6)  b1s[tid] = c1b[tid];
    if (tid < 16) b2s[tid] = c2b[tid];
    __syncthreads();
    for (int i = tid; i < 784; i += 256) {
        int r = i / 28;
        int c = i - r * 28;
        img[(r + 2) * 32 + (c + 2)] = xi[i];
    }
    __syncthreads();

    // conv1 + relu + 2x2 maxpool -> p1 (relu(max) == max(relu), relu monotone)
    for (int idx = tid; idx < 1176; idx += 256) {
        int ch  = idx / 196;
        int rem = idx - ch * 196;
        int py  = rem / 14;
        int px  = rem - py * 14;
        float wr[25];
        {
            const float* wc = &w1s[ch * 25];
            #pragma unroll
            for (int k = 0; k < 25; ++k) wr[k] = wc[k];
        }
        float patch[36];
        {
            const float* ib = &img[(2 * py) * 32 + 2 * px];
            #pragma unroll
            for (int r = 0; r < 6; ++r)
                #pragma unroll
                for (int c = 0; c < 6; ++c)
                    patch[r * 6 + c] = ib[r * 32 + c];
        }
        float b = b1s[ch];
        float m = -1e30f;
        #pragma unroll
        for (int dy = 0; dy < 2; ++dy)
            #pragma unroll
            for (int dx = 0; dx < 2; ++dx) {
                float acc = b;
                #pragma unroll
                for (int ky = 0; ky < 5; ++ky)
                    #pragma unroll
                    for (int kx = 0; kx < 5; ++kx)
                        acc += patch[(dy + ky) * 6 + (dx + kx)] * wr[ky * 5 + kx];
                m = fmaxf(m, acc);
            }
        p1[idx] = fmaxf(m, 0.f);
    }
    __syncthreads();

    // conv2 (valid) + relu + pool: each thread computes a 2x2 conv quad =
    // exactly one pool window. h flatten order: ch*25 + qy*5 + qx.
    for (int q = tid; q < 400; q += 256) {
        int ch  = q / 25;
        int rem = q - ch * 25;
        int qy  = rem / 5;
        int qx  = rem - qy * 5;
        const int y0 = qy * 2, x0 = qx * 2;
        float b = b2s[ch];
        float a00 = b, a01 = b, a10 = b, a11 = b;
        for (int ci = 0; ci < 6; ++ci) {
            float wr[25];
            {
                const float* wc = &w2s[ch * 150 + ci * 25];
                #pragma unroll
                for (int k = 0; k < 25; ++k) wr[k] = wc[k];
            }
            float patch[36];
            {
                const float* pb = &p1[ci * 196 + y0 * 14 + x0];
                #pragma unroll
                for (int r = 0; r < 6; ++r)
                    #pragma unroll
                    for (int c = 0; c < 6; ++c)
                        patch[r * 6 + c] = pb[r * 14 + c];
            }
            #pragma unroll
            for (int ky = 0; ky < 5; ++ky)
                #pragma unroll
                for (int kx = 0; kx < 5; ++kx) {
                    float w = wr[ky * 5 + kx];
                    a00 += patch[ky * 6 + kx] * w;
                    a01 += patch[ky * 6 + kx + 1] * w;
                    a10 += patch[(ky + 1) * 6 + kx] * w;
                    a11 += patch[(ky + 1) * 6 + kx + 1] * w;
                }
        }
        float m = fmaxf(fmaxf(a00, a01), fmaxf(a10, a11));
        hout[(size_t)n * 400 + q] = fmaxf(m, 0.f);
    }
}

// ---------------------------------------------------------------------------
// Kernel B: fused fc1+fc2+fc3. 1 block = 32 images, 256 threads.
// Thread tile = 4 images x 4 outputs (8 LDS reads / 16 FMAs). Weight chunks
// staged in LDS (strides 51/61/85/121: coprime to 32 -> conflict-free).
// ---------------------------------------------------------------------------
__global__ __launch_bounds__(256) void lenet_fc(
    const float* __restrict__ h,
    const float* __restrict__ f1w, const float* __restrict__ f1b,
    const float* __restrict__ f2w, const float* __restrict__ f2b,
    const float* __restrict__ f3w, const float* __restrict__ f3b,
    float* __restrict__ emb, int N)
{
    __shared__ float hs[32 * 51];    // h chunk [32][50] padded
    __shared__ float ws[120 * 51];   // weight chunk (largest user: fc1)
    __shared__ float a1[32 * 121];   // fc1 activations [32][120] padded
    __shared__ float a2[32 * 85];    // fc2 activations [32][84] padded

    const int tid = threadIdx.x;
    const int n0 = blockIdx.x * TN;
    const int ig = tid & 7;          // image group: rows ig*4 .. ig*4+3
    const int og = tid >> 3;         // output group: cols og*4 .. og*4+3

    float acc[16];
    #pragma unroll
    for (int j = 0; j < 16; ++j) acc[j] = 0.f;

    // ---- fc1: [32,400] @ [120,400]^T, K chunked by 50 ----
    for (int kc = 0; kc < 400; kc += 50) {
        __syncthreads();
        for (int i = tid; i < 32 * 50; i += 256) {
            int r = i / 50, c = i - r * 50;
            int row = n0 + r;
            hs[r * 51 + c] = (row < N) ? h[(size_t)row * 400 + kc + c] : 0.f;
        }
        for (int i = tid; i < 120 * 50; i += 256) {
            int r = i / 50, c = i - r * 50;
            ws[r * 51 + c] = f1w[r * 400 + kc + c];
        }
        __syncthreads();
        if (og < 30) {
            for (int kk = 0; kk < 50; ++kk) {
                float h0 = hs[(ig * 4 + 0) * 51 + kk];
                float h1 = hs[(ig * 4 + 1) * 51 + kk];
                float h2 = hs[(ig * 4 + 2) * 51 + kk];
                float h3 = hs[(ig * 4 + 3) * 51 + kk];
                #pragma unroll
                for (int j = 0; j < 4; ++j) {
                    float w = ws[(og * 4 + j) * 51 + kk];
                    acc[j]      += h0 * w;
                    acc[4 + j]  += h1 * w;
                    acc[8 + j]  += h2 * w;
                    acc[12 + j] += h3 * w;
                }
            }
        }
    }
    __syncthreads();
    if (og < 30) {
        #pragma unroll
        for (int j = 0; j < 4; ++j) {
            int o = og * 4 + j;
            float bb = f1b[o];
            a1[(ig * 4 + 0) * 121 + o] = fmaxf(acc[j]      + bb, 0.f);
            a1[(ig * 4 + 1) * 121 + o] = fmaxf(acc[4 + j]  + bb, 0.f);
            a1[(ig * 4 + 2) * 121 + o] = fmaxf(acc[8 + j]  + bb, 0.f);
            a1[(ig * 4 + 3) * 121 + o] = fmaxf(acc[12 + j] + bb, 0.f);
        }
    }
    #pragma unroll
    for (int j = 0; j < 16; ++j) acc[j] = 0.f;

    // ---- fc2: [32,120] @ [84,120]^T, K chunked by 60 ----
    for (int kc = 0; kc < 120; kc += 60) {
        __syncthreads();
        for (int i = tid; i < 84 * 60; i += 256) {
            int r = i / 60, c = i - r * 60;
            ws[r * 61 + c] = f2w[r * 120 + kc + c];
        }
        __syncthreads();
        if (og < 21) {
            for (int kk = 0; kk < 60; ++kk) {
                float h0 = a1[(ig * 4 + 0) * 121 + kc + kk];
                float h1 = a1[(ig * 4 + 1) * 121 + kc + kk];
                float h2 = a1[(ig * 4 + 2) * 121 + kc + kk];
                float h3 = a1[(ig * 4 + 3) * 121 + kc + kk];
                #pragma unroll
                for (int j = 0; j < 4; ++j) {
                    float w = ws[(og * 4 + j) * 61 + kk];
                    acc[j]      += h0 * w;
                    acc[4 + j]  += h1 * w;
                    acc[8 + j]  += h2 * w;
                    acc[12 + j] += h3 * w;
                }
            }
        }
    }
    __syncthreads();
    if (og < 21) {
        #pragma unroll
        for (int j = 0; j < 4; ++j) {
            int o = og * 4 + j;
            float bb = f2b[o];
            a2[(ig * 4 + 0) * 85 + o] = fmaxf(acc[j]      + bb, 0.f);
            a2[(ig * 4 + 1) * 85 + o] = fmaxf(acc[4 + j]  + bb, 0.f);
            a2[(ig * 4 + 2) * 85 + o] = fmaxf(acc[8 + j]  + bb, 0.f);
            a2[(ig * 4 + 3) * 85 + o] = fmaxf(acc[12 + j] + bb, 0.f);
        }
    }
    // stage w3 fully: [64][84] -> stride 85
    for (int i = tid; i < 64 * 84; i += 256) {
        int r = i / 84, c = i - r * 84;
        ws[r * 85 + c] = f3w[i];
    }
    #pragma unroll
    for (int j = 0; j < 16; ++j) acc[j] = 0.f;
    __syncthreads();

    // ---- fc3: [32,84] @ [64,84]^T (no relu), write emb ----
    if (og < 16) {
        for (int kk = 0; kk < 84; ++kk) {
            float h0 = a2[(ig * 4 + 0) * 85 + kk];
            float h1 = a2[(ig * 4 + 1) * 85 + kk];
            float h2 = a2[(ig * 4 + 2) * 85 + kk];
            float h3 = a2[(ig * 4 + 3) * 85 + kk];
            #pragma unroll
            for (int j = 0; j < 4; ++j) {
                float w = ws[(og * 4 + j) * 85 + kk];
                acc[j]      += h0 * w;
                acc[4 + j]  += h1 * w;
                acc[8 + j]  += h2 * w;
                acc[12 + j] += h3 * w;
            }
        }
        #pragma unroll
        for (int j = 0; j < 4; ++j) {
            int o = og * 4 + j;
            float bb = f3b[o];
            #pragma unroll
            for (int r = 0; r < 4; ++r) {
                int row = n0 + ig * 4 + r;
                if (row < N)
                    emb[(size_t)row * 64 + o] = acc[r * 4 + j] + bb;
            }
        }
    }
}

// ---------------------------------------------------------------------------
// Kernel C: softmax over 64 dims + |s - proto|, proto = emb[0]/5.
// One wave per row; lane = embedding dim.
// ---------------------------------------------------------------------------
__global__ __launch_bounds__(256) void proto_head(
    const float* __restrict__ emb, float* __restrict__ out, int N)
{
    int row  = blockIdx.x * 4 + (threadIdx.x >> 6);
    int lane = threadIdx.x & 63;
    if (row >= N) return;
    float v = emb[(size_t)row * 64 + lane];
    float m = v;
    #pragma unroll
    for (int off = 32; off >= 1; off >>= 1)
        m = fmaxf(m, __shfl_xor(m, off));
    float e = __expf(v - m);
    float s = e;
    #pragma unroll
    for (int off = 32; off >= 1; off >>= 1)
        s += __shfl_xor(s, off);
    float sm = e / s;
    float proto = emb[lane] * 0.2f;   // emb[0][lane] / NUM_CLASSES
    out[(size_t)row * 64 + lane] = fabsf(sm - proto);
}

extern "C" void kernel_launch(void* const* d_in, const int* in_sizes, int n_in,
                              void* d_out, int out_size, void* d_ws, size_t ws_size,
                              hipStream_t stream)
{
    const float* x   = (const float*)d_in[0];
    const float* c1w = (const float*)d_in[1];
    const float* c1b = (const float*)d_in[2];
    const float* c2w = (const float*)d_in[3];
    const float* c2b = (const float*)d_in[4];
    const float* f1w = (const float*)d_in[5];
    const float* f1b = (const float*)d_in[6];
    const float* f2w = (const float*)d_in[7];
    const float* f2b = (const float*)d_in[8];
    const float* f3w = (const float*)d_in[9];
    const float* f3b = (const float*)d_in[10];
    float* out = (float*)d_out;

    const int N = in_sizes[0] / 784;          // 20480
    float* h   = (float*)d_ws;                // [N,400]
    float* emb = h + (size_t)N * 400;         // [N,64]

    lenet_conv<<<N, 256, 0, stream>>>(x, c1w, c1b, c2w, c2b, h, N);
    lenet_fc<<<(N + TN - 1) / TN, 256, 0, stream>>>(h, f1w, f1b, f2w, f2b,
                                                    f3w, f3b, emb, N);
    proto_head<<<(N + 3) / 4, 256, 0, stream>>>(emb, out, N);
}

// Round 2
// 371.391 us; speedup vs baseline: 1.5774x; 1.5774x over previous
//
#include <hip/hip_runtime.h>

// ---------------------------------------------------------------------------
// Batch-inner LeNet: lane = image. All activations in [feature][N] layout ->
// coalesced global loads (SGPR base + lane offset), weights broadcast from
// LDS (conflict-free), ~8 FMAs per weight read -> VALU-bound.
// ---------------------------------------------------------------------------

// Transpose x[nc,784] -> xt[784,nc], 64x64 LDS tiles.
__global__ __launch_bounds__(256) void transpose_x(
    const float* __restrict__ x, float* __restrict__ xt, int nc)
{
    __shared__ float t[64][65];
    const int tx = threadIdx.x & 63, ty = threadIdx.x >> 6;  // ty 0..3
    const int p0 = blockIdx.x * 64, n0 = blockIdx.y * 64;
    #pragma unroll
    for (int rr = 0; rr < 16; ++rr) {
        int nl = rr * 4 + ty;
        int p = p0 + tx;
        float v = 0.f;
        if (p < 784) v = x[(size_t)(n0 + nl) * 784 + p];
        t[tx][nl] = v;
    }
    __syncthreads();
    #pragma unroll
    for (int rr = 0; rr < 16; ++rr) {
        int pl = rr * 4 + ty;
        int p = p0 + pl;
        if (p < 784)
            xt[(size_t)p * nc + n0 + tx] = t[pl][tx];
    }
}

// conv1(pad2)+relu+pool. Block = 512 images (2 per thread) at ONE pooled
// position. grid = (196, nc/512). Writes p1t[1176][nc].
__global__ __launch_bounds__(256, 2) void conv1_bt(
    const float* __restrict__ xt, const float* __restrict__ c1w,
    const float* __restrict__ c1b, float* __restrict__ p1t, int nc)
{
    __shared__ float w1s[6 * 28];
    __shared__ float b1s[6];
    const int tid = threadIdx.x;
    if (tid < 150) { int ch = tid / 25, k = tid - ch * 25; w1s[ch * 28 + k] = c1w[tid]; }
    if (tid < 6) b1s[tid] = c1b[tid];
    __syncthreads();

    const int pos = blockIdx.x;              // 0..195
    const int py = pos / 14, px = pos - py * 14;
    const int ia = blockIdx.y * 512 + tid;   // image A
    const int ib = ia + 256;                 // image B
    const int y0 = 2 * py - 2, x0 = 2 * px - 2;

    float pa[36], pb[36];
    #pragma unroll
    for (int r = 0; r < 6; ++r) {
        int iy = y0 + r;
        bool yok = (iy >= 0) && (iy < 28);
        #pragma unroll
        for (int cc = 0; cc < 6; ++cc) {
            int ix = x0 + cc;
            float va = 0.f, vb = 0.f;
            if (yok && (ix >= 0) && (ix < 28)) {
                const float* p = &xt[(size_t)(iy * 28 + ix) * nc];
                va = p[ia]; vb = p[ib];
            }
            pa[r * 6 + cc] = va; pb[r * 6 + cc] = vb;
        }
    }

    #pragma unroll
    for (int ch = 0; ch < 6; ++ch) {
        float w[25];
        const float4* wq = (const float4*)&w1s[ch * 28];
        #pragma unroll
        for (int q = 0; q < 6; ++q) {
            float4 t = wq[q];
            w[4*q] = t.x; w[4*q+1] = t.y; w[4*q+2] = t.z; w[4*q+3] = t.w;
        }
        w[24] = w1s[ch * 28 + 24];
        float b = b1s[ch];
        float ma = -1e30f, mb = -1e30f;
        #pragma unroll
        for (int dy = 0; dy < 2; ++dy)
        #pragma unroll
        for (int dx = 0; dx < 2; ++dx) {
            float aa = b, ab = b;
            #pragma unroll
            for (int ky = 0; ky < 5; ++ky)
            #pragma unroll
            for (int kx = 0; kx < 5; ++kx) {
                float ww = w[ky * 5 + kx];
                aa += pa[(dy + ky) * 6 + dx + kx] * ww;
                ab += pb[(dy + ky) * 6 + dx + kx] * ww;
            }
            ma = fmaxf(ma, aa); mb = fmaxf(mb, ab);
        }
        float* o = &p1t[(size_t)(ch * 196 + pos) * nc];
        o[ia] = fmaxf(ma, 0.f);
        o[ib] = fmaxf(mb, 0.f);
    }
}

// conv2(valid)+relu+pool. Block = 512 images at ONE pool-quad position.
// 2 oc-passes of 8 (acc 64). grid = (25, nc/512). Writes ht[400][nc],
// feature order ch*25 + qy*5 + qx (matches reference flatten).
__global__ __launch_bounds__(256, 2) void conv2_bt(
    const float* __restrict__ p1t, const float* __restrict__ c2w,
    const float* __restrict__ c2b, float* __restrict__ ht, int nc)
{
    __shared__ float w2s[96 * 28];   // [oc*6+ci][28]
    __shared__ float b2s[16];
    const int tid = threadIdx.x;
    for (int i = tid; i < 2400; i += 256) {
        int g = i / 25, k = i - g * 25;
        w2s[g * 28 + k] = c2w[i];
    }
    if (tid < 16) b2s[tid] = c2b[tid];
    __syncthreads();

    const int pos = blockIdx.x;              // 0..24
    const int qy = pos / 5, qx = pos - qy * 5;
    const int ia = blockIdx.y * 512 + tid, ib = ia + 256;
    const int y0 = 2 * qy, x0 = 2 * qx;

    for (int pass = 0; pass < 2; ++pass) {
        float acc[64];
        #pragma unroll
        for (int i = 0; i < 64; ++i) acc[i] = 0.f;
        for (int ci = 0; ci < 6; ++ci) {
            float pa[36], pb[36];
            #pragma unroll
            for (int r = 0; r < 6; ++r)
                #pragma unroll
                for (int cc = 0; cc < 6; ++cc) {
                    const float* p = &p1t[(size_t)(ci * 196 + (y0 + r) * 14 + x0 + cc) * nc];
                    pa[r * 6 + cc] = p[ia];
                    pb[r * 6 + cc] = p[ib];
                }
            #pragma unroll
            for (int o8 = 0; o8 < 8; ++o8) {
                float w[25];
                const int wb = ((pass * 8 + o8) * 6 + ci) * 28;
                const float4* wq = (const float4*)&w2s[wb];
                #pragma unroll
                for (int q = 0; q < 6; ++q) {
                    float4 t = wq[q];
                    w[4*q] = t.x; w[4*q+1] = t.y; w[4*q+2] = t.z; w[4*q+3] = t.w;
                }
                w[24] = w2s[wb + 24];
                #pragma unroll
                for (int ky = 0; ky < 5; ++ky)
                #pragma unroll
                for (int kx = 0; kx < 5; ++kx) {
                    float ww = w[ky * 5 + kx];
                    acc[o8*8+0] += pa[ky*6+kx]       * ww;
                    acc[o8*8+1] += pa[ky*6+kx+1]     * ww;
                    acc[o8*8+2] += pa[(ky+1)*6+kx]   * ww;
                    acc[o8*8+3] += pa[(ky+1)*6+kx+1] * ww;
                    acc[o8*8+4] += pb[ky*6+kx]       * ww;
                    acc[o8*8+5] += pb[ky*6+kx+1]     * ww;
                    acc[o8*8+6] += pb[(ky+1)*6+kx]   * ww;
                    acc[o8*8+7] += pb[(ky+1)*6+kx+1] * ww;
                }
            }
        }
        #pragma unroll
        for (int o8 = 0; o8 < 8; ++o8) {
            int oc = pass * 8 + o8;
            float b = b2s[oc];
            float ma = fmaxf(fmaxf(acc[o8*8+0], acc[o8*8+1]),
                             fmaxf(acc[o8*8+2], acc[o8*8+3])) + b;
            float mb = fmaxf(fmaxf(acc[o8*8+4], acc[o8*8+5]),
                             fmaxf(acc[o8*8+6], acc[o8*8+7])) + b;
            float* o = &ht[(size_t)(oc * 25 + pos) * nc];
            o[ia] = fmaxf(ma, 0.f);
            o[ib] = fmaxf(mb, 0.f);
        }
    }
}

// fc1+fc2+fc3 fused. Block = 32 images. fc1: h read direct from ht (L2,
// coalesced, VMEM pipe), weights via swizzled conflict-free ds_read_b128.
__global__ __launch_bounds__(256, 2) void lenet_fc_t(
    const float* __restrict__ ht,
    const float* __restrict__ f1w, const float* __restrict__ f1b,
    const float* __restrict__ f2w, const float* __restrict__ f2b,
    const float* __restrict__ f3w, const float* __restrict__ f3b,
    float* __restrict__ emb, int nc)
{
    __shared__ float wpool[6400];    // fc1: swizzled [50][128]; fc2/fc3 reuse
    __shared__ float a1[32 * 121];
    __shared__ float a2[32 * 85];

    const int tid = threadIdx.x;
    const int n0 = blockIdx.x * 32;
    const int ig = tid & 7;          // image group (4 rows each)
    const int og = tid >> 3;         // output group (4 outs each)

    float acc[16];
    #pragma unroll
    for (int j = 0; j < 16; ++j) acc[j] = 0.f;

    // ---- fc1: [32,400] @ [120,400]^T, K chunks of 50 ----
    for (int kc = 0; kc < 400; kc += 50) {
        __syncthreads();
        for (int i = tid; i < 6000; i += 256) {
            int r = i / 50, c = i - r * 50;          // r: out 0..119
            int rg = r >> 2, rl = r & 3;
            wpool[c * 128 + (((rg ^ (c & 7)) << 2) | rl)] = f1w[r * 400 + kc + c];
        }
        __syncthreads();
        if (og < 30) {
            #pragma unroll 2
            for (int kk = 0; kk < 50; ++kk) {
                const float* hp = &ht[(size_t)(kc + kk) * nc + n0 + ig * 4];
                float h0 = hp[0], h1 = hp[1], h2 = hp[2], h3 = hp[3];
                float4 wv = *(const float4*)&wpool[kk * 128 + ((og ^ (kk & 7)) << 2)];
                acc[0]  += h0 * wv.x; acc[1]  += h0 * wv.y;
                acc[2]  += h0 * wv.z; acc[3]  += h0 * wv.w;
                acc[4]  += h1 * wv.x; acc[5]  += h1 * wv.y;
                acc[6]  += h1 * wv.z; acc[7]  += h1 * wv.w;
                acc[8]  += h2 * wv.x; acc[9]  += h2 * wv.y;
                acc[10] += h2 * wv.z; acc[11] += h2 * wv.w;
                acc[12] += h3 * wv.x; acc[13] += h3 * wv.y;
                acc[14] += h3 * wv.z; acc[15] += h3 * wv.w;
            }
        }
    }
    __syncthreads();
    if (og < 30) {
        #pragma unroll
        for (int j = 0; j < 4; ++j) {
            int o = og * 4 + j;
            float bb = f1b[o];
            a1[(ig * 4 + 0) * 121 + o] = fmaxf(acc[j]      + bb, 0.f);
            a1[(ig * 4 + 1) * 121 + o] = fmaxf(acc[4 + j]  + bb, 0.f);
            a1[(ig * 4 + 2) * 121 + o] = fmaxf(acc[8 + j]  + bb, 0.f);
            a1[(ig * 4 + 3) * 121 + o] = fmaxf(acc[12 + j] + bb, 0.f);
        }
    }
    #pragma unroll
    for (int j = 0; j < 16; ++j) acc[j] = 0.f;

    // ---- fc2: [32,120] @ [84,120]^T, K chunks of 60, weights [84][61] ----
    for (int kc = 0; kc < 120; kc += 60) {
        __syncthreads();
        for (int i = tid; i < 84 * 60; i += 256) {
            int r = i / 60, c = i - r * 60;
            wpool[r * 61 + c] = f2w[r * 120 + kc + c];
        }
        __syncthreads();
        if (og < 21) {
            for (int kk = 0; kk < 60; ++kk) {
                float h0 = a1[(ig * 4 + 0) * 121 + kc + kk];
                float h1 = a1[(ig * 4 + 1) * 121 + kc + kk];
                float h2 = a1[(ig * 4 + 2) * 121 + kc + kk];
                float h3 = a1[(ig * 4 + 3) * 121 + kc + kk];
                #pragma unroll
                for (int j = 0; j < 4; ++j) {
                    float w = wpool[(og * 4 + j) * 61 + kk];
                    acc[j]      += h0 * w;
                    acc[4 + j]  += h1 * w;
                    acc[8 + j]  += h2 * w;
                    acc[12 + j] += h3 * w;
                }
            }
        }
    }
    __syncthreads();
    if (og < 21) {
        #pragma unroll
        for (int j = 0; j < 4; ++j) {
            int o = og * 4 + j;
            float bb = f2b[o];
            a2[(ig * 4 + 0) * 85 + o] = fmaxf(acc[j]      + bb, 0.f);
            a2[(ig * 4 + 1) * 85 + o] = fmaxf(acc[4 + j]  + bb, 0.f);
            a2[(ig * 4 + 2) * 85 + o] = fmaxf(acc[8 + j]  + bb, 0.f);
            a2[(ig * 4 + 3) * 85 + o] = fmaxf(acc[12 + j] + bb, 0.f);
        }
    }
    // stage f3w [64][84] -> [64][85]
    for (int i = tid; i < 64 * 84; i += 256) {
        int r = i / 84, c = i - r * 84;
        wpool[r * 85 + c] = f3w[i];
    }
    #pragma unroll
    for (int j = 0; j < 16; ++j) acc[j] = 0.f;
    __syncthreads();

    // ---- fc3: [32,84] @ [64,84]^T (no relu) ----
    if (og < 16) {
        for (int kk = 0; kk < 84; ++kk) {
            float h0 = a2[(ig * 4 + 0) * 85 + kk];
            float h1 = a2[(ig * 4 + 1) * 85 + kk];
            float h2 = a2[(ig * 4 + 2) * 85 + kk];
            float h3 = a2[(ig * 4 + 3) * 85 + kk];
            #pragma unroll
            for (int j = 0; j < 4; ++j) {
                float w = wpool[(og * 4 + j) * 85 + kk];
                acc[j]      += h0 * w;
                acc[4 + j]  += h1 * w;
                acc[8 + j]  += h2 * w;
                acc[12 + j] += h3 * w;
            }
        }
    }
    __syncthreads();                  // a1 now dead -> reuse as emb stage
    if (og < 16) {
        #pragma unroll
        for (int j = 0; j < 4; ++j) {
            int o = og * 4 + j;
            float bb = f3b[o];
            #pragma unroll
            for (int r = 0; r < 4; ++r)
                a1[(ig * 4 + r) * 67 + o] = acc[r * 4 + j] + bb;
        }
    }
    __syncthreads();
    for (int i = tid; i < 2048; i += 256) {
        int row = i >> 6, o = i & 63;
        emb[(size_t)(n0 + row) * 64 + o] = a1[row * 67 + o];
    }
}

// softmax(64) + |s - proto|, proto = emb[0]/5. One wave per row.
__global__ __launch_bounds__(256) void proto_head(
    const float* __restrict__ emb, float* __restrict__ out, int N)
{
    int row  = blockIdx.x * 4 + (threadIdx.x >> 6);
    int lane = threadIdx.x & 63;
    if (row >= N) return;
    float v = emb[(size_t)row * 64 + lane];
    float m = v;
    #pragma unroll
    for (int off = 32; off >= 1; off >>= 1)
        m = fmaxf(m, __shfl_xor(m, off));
    float e = expf(v - m);
    float s = e;
    #pragma unroll
    for (int off = 32; off >= 1; off >>= 1)
        s += __shfl_xor(s, off);
    float sm = e / s;
    float proto = emb[lane] * 0.2f;
    out[(size_t)row * 64 + lane] = fabsf(sm - proto);
}

extern "C" void kernel_launch(void* const* d_in, const int* in_sizes, int n_in,
                              void* d_out, int out_size, void* d_ws, size_t ws_size,
                              hipStream_t stream)
{
    const float* x   = (const float*)d_in[0];
    const float* c1w = (const float*)d_in[1];
    const float* c1b = (const float*)d_in[2];
    const float* c2w = (const float*)d_in[3];
    const float* c2b = (const float*)d_in[4];
    const float* f1w = (const float*)d_in[5];
    const float* f1b = (const float*)d_in[6];
    const float* f2w = (const float*)d_in[7];
    const float* f2b = (const float*)d_in[8];
    const float* f3w = (const float*)d_in[9];
    const float* f3b = (const float*)d_in[10];
    float* out = (float*)d_out;

    const int N = in_sizes[0] / 784;          // 20480
    float* base = (float*)d_ws;

    // chunk count: per chunk need xt(784nc) [aliased by ht(400nc)] +
    // p1t(1176nc) + emb(64N persistent) floats = 7840nc + 256N bytes.
    int c = 40;                               // last-resort nc=512
    const int cands[] = {1, 2, 4, 5, 8, 10, 20, 40};
    for (int k = 0; k < 8; ++k) {
        int cd = cands[k];
        if (N % cd) continue;
        int ncq = N / cd;
        if (ncq % 512) continue;
        size_t need = (size_t)7840 * ncq + (size_t)256 * N;
        if (need <= ws_size) { c = cd; break; }
    }
    const int nc = N / c;

    float* xt  = base;                        // [784][nc]
    float* p1t = base + (size_t)784 * nc;     // [1176][nc]
    float* ht_ = base;                        // [400][nc], aliases xt (dead)
    float* emb = base + (size_t)1960 * nc;    // [N][64]

    for (int k = 0; k < c; ++k) {
        int n0 = k * nc;
        transpose_x<<<dim3(13, nc / 64), 256, 0, stream>>>(
            x + (size_t)n0 * 784, xt, nc);
        conv1_bt<<<dim3(196, nc / 512), 256, 0, stream>>>(
            xt, c1w, c1b, p1t, nc);
        conv2_bt<<<dim3(25, nc / 512), 256, 0, stream>>>(
            p1t, c2w, c2b, ht_, nc);
        lenet_fc_t<<<nc / 32, 256, 0, stream>>>(
            ht_, f1w, f1b, f2w, f2b, f3w, f3b, emb + (size_t)n0 * 64, nc);
    }
    proto_head<<<(N + 3) / 4, 256, 0, stream>>>(emb, out, N);
}

// Round 3
// 344.434 us; speedup vs baseline: 1.7009x; 1.0783x over previous
//
#include <hip/hip_runtime.h>

// ---------------------------------------------------------------------------
// Batch-inner LeNet: lane = image, activations in [feature][N] layout.
// Convs use a flattened grid + bijective XCD swizzle (consecutive newids on
// one XCD) so all position-blocks of an image group share that XCD's L2.
// ---------------------------------------------------------------------------

__device__ __forceinline__ int xcd_swizzle(int orig, int nwg) {
    // m204 bijective: xcd = orig%8 gets a contiguous newid range.
    int xcd = orig & 7, q = nwg >> 3, r = nwg & 7;
    int base = (xcd < r) ? xcd * (q + 1) : r * (q + 1) + (xcd - r) * q;
    return base + (orig >> 3);
}

// Transpose x[nc,784] -> xt[784,nc], 64x64 LDS tiles.
__global__ __launch_bounds__(256) void transpose_x(
    const float* __restrict__ x, float* __restrict__ xt, int nc)
{
    __shared__ float t[64][65];
    const int tx = threadIdx.x & 63, ty = threadIdx.x >> 6;  // ty 0..3
    const int p0 = blockIdx.x * 64, n0 = blockIdx.y * 64;
    #pragma unroll
    for (int rr = 0; rr < 16; ++rr) {
        int nl = rr * 4 + ty;
        int p = p0 + tx;
        float v = 0.f;
        if (p < 784) v = x[(size_t)(n0 + nl) * 784 + p];
        t[tx][nl] = v;
    }
    __syncthreads();
    #pragma unroll
    for (int rr = 0; rr < 16; ++rr) {
        int pl = rr * 4 + ty;
        int p = p0 + pl;
        if (p < 784)
            xt[(size_t)p * nc + n0 + tx] = t[pl][tx];
    }
}

// conv1(pad2)+relu+pool. Flat grid = 196*(nc/512); after swizzle,
// grp = img block of 512 (2 per thread), pos = pooled position.
__global__ __launch_bounds__(256, 2) void conv1_bt(
    const float* __restrict__ xt, const float* __restrict__ c1w,
    const float* __restrict__ c1b, float* __restrict__ p1t, int nc)
{
    __shared__ float w1s[6 * 28];
    __shared__ float b1s[6];
    const int tid = threadIdx.x;
    if (tid < 150) { int ch = tid / 25, k = tid - ch * 25; w1s[ch * 28 + k] = c1w[tid]; }
    if (tid < 6) b1s[tid] = c1b[tid];

    const int newid = xcd_swizzle(blockIdx.x, gridDim.x);
    const int grp = newid / 196, pos = newid - grp * 196;
    const int py = pos / 14, px = pos - py * 14;
    const int ia = grp * 512 + tid;          // image A
    const int ib = ia + 256;                 // image B
    const int y0 = 2 * py - 2, x0 = 2 * px - 2;
    __syncthreads();

    float pa[36], pb[36];
    #pragma unroll
    for (int r = 0; r < 6; ++r) {
        int iy = y0 + r;
        bool yok = (iy >= 0) && (iy < 28);
        #pragma unroll
        for (int cc = 0; cc < 6; ++cc) {
            int ix = x0 + cc;
            float va = 0.f, vb = 0.f;
            if (yok && (ix >= 0) && (ix < 28)) {
                const float* p = &xt[(size_t)(iy * 28 + ix) * nc];
                va = p[ia]; vb = p[ib];
            }
            pa[r * 6 + cc] = va; pb[r * 6 + cc] = vb;
        }
    }

    #pragma unroll
    for (int ch = 0; ch < 6; ++ch) {
        float w[25];
        const float4* wq = (const float4*)&w1s[ch * 28];
        #pragma unroll
        for (int q = 0; q < 6; ++q) {
            float4 t = wq[q];
            w[4*q] = t.x; w[4*q+1] = t.y; w[4*q+2] = t.z; w[4*q+3] = t.w;
        }
        w[24] = w1s[ch * 28 + 24];
        float b = b1s[ch];
        float ma = -1e30f, mb = -1e30f;
        #pragma unroll
        for (int dy = 0; dy < 2; ++dy)
        #pragma unroll
        for (int dx = 0; dx < 2; ++dx) {
            float aa = b, ab = b;
            #pragma unroll
            for (int ky = 0; ky < 5; ++ky)
            #pragma unroll
            for (int kx = 0; kx < 5; ++kx) {
                float ww = w[ky * 5 + kx];
                aa += pa[(dy + ky) * 6 + dx + kx] * ww;
                ab += pb[(dy + ky) * 6 + dx + kx] * ww;
            }
            ma = fmaxf(ma, aa); mb = fmaxf(mb, ab);
        }
        float* o = &p1t[(size_t)(ch * 196 + pos) * nc];
        o[ia] = fmaxf(ma, 0.f);
        o[ib] = fmaxf(mb, 0.f);
    }
}

// conv2(valid)+relu+pool, single pass: 1 image/thread, all 16 oc (acc[64]),
// patches loaded once per ci. Flat grid = 25*(nc/256) with XCD swizzle.
// Feature order ch*25 + qy*5 + qx matches reference flatten.
__global__ __launch_bounds__(256, 2) void conv2_bt(
    const float* __restrict__ p1t, const float* __restrict__ c2w,
    const float* __restrict__ c2b, float* __restrict__ ht, int nc)
{
    __shared__ float w2s[96 * 28];   // [oc*6+ci][28]
    __shared__ float b2s[16];
    const int tid = threadIdx.x;
    for (int i = tid; i < 2400; i += 256) {
        int g = i / 25, k = i - g * 25;
        w2s[g * 28 + k] = c2w[i];
    }
    if (tid < 16) b2s[tid] = c2b[tid];

    const int newid = xcd_swizzle(blockIdx.x, gridDim.x);
    const int grp = newid / 25, pos = newid - grp * 25;
    const int qy = pos / 5, qx = pos - qy * 5;
    const int img = grp * 256 + tid;
    const int y0 = 2 * qy, x0 = 2 * qx;
    __syncthreads();

    float acc[64];
    #pragma unroll
    for (int i = 0; i < 64; ++i) acc[i] = 0.f;

    #pragma unroll 1
    for (int ci = 0; ci < 6; ++ci) {
        float pa[36];
        #pragma unroll
        for (int r = 0; r < 6; ++r)
            #pragma unroll
            for (int cc = 0; cc < 6; ++cc)
                pa[r * 6 + cc] =
                    p1t[(size_t)(ci * 196 + (y0 + r) * 14 + x0 + cc) * nc + img];
        #pragma unroll
        for (int oc = 0; oc < 16; ++oc) {
            float w[25];
            const int wb = (oc * 6 + ci) * 28;
            const float4* wq = (const float4*)&w2s[wb];
            #pragma unroll
            for (int q = 0; q < 6; ++q) {
                float4 t = wq[q];
                w[4*q] = t.x; w[4*q+1] = t.y; w[4*q+2] = t.z; w[4*q+3] = t.w;
            }
            w[24] = w2s[wb + 24];
            #pragma unroll
            for (int ky = 0; ky < 5; ++ky)
            #pragma unroll
            for (int kx = 0; kx < 5; ++kx) {
                float ww = w[ky * 5 + kx];
                acc[oc*4+0] += pa[ky*6+kx]       * ww;
                acc[oc*4+1] += pa[ky*6+kx+1]     * ww;
                acc[oc*4+2] += pa[(ky+1)*6+kx]   * ww;
                acc[oc*4+3] += pa[(ky+1)*6+kx+1] * ww;
            }
        }
    }
    #pragma unroll
    for (int oc = 0; oc < 16; ++oc) {
        float b = b2s[oc];
        float m = fmaxf(fmaxf(acc[oc*4+0], acc[oc*4+1]),
                        fmaxf(acc[oc*4+2], acc[oc*4+3])) + b;
        ht[(size_t)(oc * 25 + pos) * nc + img] = fmaxf(m, 0.f);
    }
}

// fc1+fc2+fc3 fused. Block = 32 images. fc1: h read direct from ht (L2,
// coalesced, VMEM pipe), weights via swizzled conflict-free ds_read_b128.
__global__ __launch_bounds__(256, 2) void lenet_fc_t(
    const float* __restrict__ ht,
    const float* __restrict__ f1w, const float* __restrict__ f1b,
    const float* __restrict__ f2w, const float* __restrict__ f2b,
    const float* __restrict__ f3w, const float* __restrict__ f3b,
    float* __restrict__ emb, int nc)
{
    __shared__ float wpool[6400];    // fc1: swizzled [50][128]; fc2/fc3 reuse
    __shared__ float a1[32 * 121];
    __shared__ float a2[32 * 85];

    const int tid = threadIdx.x;
    const int n0 = blockIdx.x * 32;
    const int ig = tid & 7;          // image group (4 rows each)
    const int og = tid >> 3;         // output group (4 outs each)

    float acc[16];
    #pragma unroll
    for (int j = 0; j < 16; ++j) acc[j] = 0.f;

    // ---- fc1: [32,400] @ [120,400]^T, K chunks of 50 ----
    for (int kc = 0; kc < 400; kc += 50) {
        __syncthreads();
        for (int i = tid; i < 6000; i += 256) {
            int r = i / 50, c = i - r * 50;          // r: out 0..119
            int rg = r >> 2, rl = r & 3;
            wpool[c * 128 + (((rg ^ (c & 7)) << 2) | rl)] = f1w[r * 400 + kc + c];
        }
        __syncthreads();
        if (og < 30) {
            #pragma unroll 2
            for (int kk = 0; kk < 50; ++kk) {
                const float* hp = &ht[(size_t)(kc + kk) * nc + n0 + ig * 4];
                float h0 = hp[0], h1 = hp[1], h2 = hp[2], h3 = hp[3];
                float4 wv = *(const float4*)&wpool[kk * 128 + ((og ^ (kk & 7)) << 2)];
                acc[0]  += h0 * wv.x; acc[1]  += h0 * wv.y;
                acc[2]  += h0 * wv.z; acc[3]  += h0 * wv.w;
                acc[4]  += h1 * wv.x; acc[5]  += h1 * wv.y;
                acc[6]  += h1 * wv.z; acc[7]  += h1 * wv.w;
                acc[8]  += h2 * wv.x; acc[9]  += h2 * wv.y;
                acc[10] += h2 * wv.z; acc[11] += h2 * wv.w;
                acc[12] += h3 * wv.x; acc[13] += h3 * wv.y;
                acc[14] += h3 * wv.z; acc[15] += h3 * wv.w;
            }
        }
    }
    __syncthreads();
    if (og < 30) {
        #pragma unroll
        for (int j = 0; j < 4; ++j) {
            int o = og * 4 + j;
            float bb = f1b[o];
            a1[(ig * 4 + 0) * 121 + o] = fmaxf(acc[j]      + bb, 0.f);
            a1[(ig * 4 + 1) * 121 + o] = fmaxf(acc[4 + j]  + bb, 0.f);
            a1[(ig * 4 + 2) * 121 + o] = fmaxf(acc[8 + j]  + bb, 0.f);
            a1[(ig * 4 + 3) * 121 + o] = fmaxf(acc[12 + j] + bb, 0.f);
        }
    }
    #pragma unroll
    for (int j = 0; j < 16; ++j) acc[j] = 0.f;

    // ---- fc2: [32,120] @ [84,120]^T, K chunks of 60, weights [84][61] ----
    for (int kc = 0; kc < 120; kc += 60) {
        __syncthreads();
        for (int i = tid; i < 84 * 60; i += 256) {
            int r = i / 60, c = i - r * 60;
            wpool[r * 61 + c] = f2w[r * 120 + kc + c];
        }
        __syncthreads();
        if (og < 21) {
            for (int kk = 0; kk < 60; ++kk) {
                float h0 = a1[(ig * 4 + 0) * 121 + kc + kk];
                float h1 = a1[(ig * 4 + 1) * 121 + kc + kk];
                float h2 = a1[(ig * 4 + 2) * 121 + kc + kk];
                float h3 = a1[(ig * 4 + 3) * 121 + kc + kk];
                #pragma unroll
                for (int j = 0; j < 4; ++j) {
                    float w = wpool[(og * 4 + j) * 61 + kk];
                    acc[j]      += h0 * w;
                    acc[4 + j]  += h1 * w;
                    acc[8 + j]  += h2 * w;
                    acc[12 + j] += h3 * w;
                }
            }
        }
    }
    __syncthreads();
    if (og < 21) {
        #pragma unroll
        for (int j = 0; j < 4; ++j) {
            int o = og * 4 + j;
            float bb = f2b[o];
            a2[(ig * 4 + 0) * 85 + o] = fmaxf(acc[j]      + bb, 0.f);
            a2[(ig * 4 + 1) * 85 + o] = fmaxf(acc[4 + j]  + bb, 0.f);
            a2[(ig * 4 + 2) * 85 + o] = fmaxf(acc[8 + j]  + bb, 0.f);
            a2[(ig * 4 + 3) * 85 + o] = fmaxf(acc[12 + j] + bb, 0.f);
        }
    }
    // stage f3w [64][84] -> [64][85]
    for (int i = tid; i < 64 * 84; i += 256) {
        int r = i / 84, c = i - r * 84;
        wpool[r * 85 + c] = f3w[i];
    }
    #pragma unroll
    for (int j = 0; j < 16; ++j) acc[j] = 0.f;
    __syncthreads();

    // ---- fc3: [32,84] @ [64,84]^T (no relu) ----
    if (og < 16) {
        for (int kk = 0; kk < 84; ++kk) {
            float h0 = a2[(ig * 4 + 0) * 85 + kk];
            float h1 = a2[(ig * 4 + 1) * 85 + kk];
            float h2 = a2[(ig * 4 + 2) * 85 + kk];
            float h3 = a2[(ig * 4 + 3) * 85 + kk];
            #pragma unroll
            for (int j = 0; j < 4; ++j) {
                float w = wpool[(og * 4 + j) * 85 + kk];
                acc[j]      += h0 * w;
                acc[4 + j]  += h1 * w;
                acc[8 + j]  += h2 * w;
                acc[12 + j] += h3 * w;
            }
        }
    }
    __syncthreads();                  // a1 now dead -> reuse as emb stage
    if (og < 16) {
        #pragma unroll
        for (int j = 0; j < 4; ++j) {
            int o = og * 4 + j;
            float bb = f3b[o];
            #pragma unroll
            for (int r = 0; r < 4; ++r)
                a1[(ig * 4 + r) * 67 + o] = acc[r * 4 + j] + bb;
        }
    }
    __syncthreads();
    for (int i = tid; i < 2048; i += 256) {
        int row = i >> 6, o = i & 63;
        emb[(size_t)(n0 + row) * 64 + o] = a1[row * 67 + o];
    }
}

// softmax(64) + |s - proto|, proto = emb[0]/5. One wave per row.
__global__ __launch_bounds__(256) void proto_head(
    const float* __restrict__ emb, float* __restrict__ out, int N)
{
    int row  = blockIdx.x * 4 + (threadIdx.x >> 6);
    int lane = threadIdx.x & 63;
    if (row >= N) return;
    float v = emb[(size_t)row * 64 + lane];
    float m = v;
    #pragma unroll
    for (int off = 32; off >= 1; off >>= 1)
        m = fmaxf(m, __shfl_xor(m, off));
    float e = expf(v - m);
    float s = e;
    #pragma unroll
    for (int off = 32; off >= 1; off >>= 1)
        s += __shfl_xor(s, off);
    float sm = e / s;
    float proto = emb[lane] * 0.2f;
    out[(size_t)row * 64 + lane] = fabsf(sm - proto);
}

extern "C" void kernel_launch(void* const* d_in, const int* in_sizes, int n_in,
                              void* d_out, int out_size, void* d_ws, size_t ws_size,
                              hipStream_t stream)
{
    const float* x   = (const float*)d_in[0];
    const float* c1w = (const float*)d_in[1];
    const float* c1b = (const float*)d_in[2];
    const float* c2w = (const float*)d_in[3];
    const float* c2b = (const float*)d_in[4];
    const float* f1w = (const float*)d_in[5];
    const float* f1b = (const float*)d_in[6];
    const float* f2w = (const float*)d_in[7];
    const float* f2b = (const float*)d_in[8];
    const float* f3w = (const float*)d_in[9];
    const float* f3b = (const float*)d_in[10];
    float* out = (float*)d_out;

    const int N = in_sizes[0] / 784;          // 20480
    float* base = (float*)d_ws;

    // per chunk: xt(784nc) [aliased by ht(400nc)] + p1t(1176nc) + emb(64N)
    int c = 40;
    const int cands[] = {1, 2, 4, 5, 8, 10, 20, 40};
    for (int k = 0; k < 8; ++k) {
        int cd = cands[k];
        if (N % cd) continue;
        int ncq = N / cd;
        if (ncq % 512) continue;
        size_t need = (size_t)7840 * ncq + (size_t)256 * N;
        if (need <= ws_size) { c = cd; break; }
    }
    const int nc = N / c;

    float* xt  = base;                        // [784][nc]
    float* p1t = base + (size_t)784 * nc;     // [1176][nc]
    float* ht_ = base;                        // [400][nc], aliases xt (dead)
    float* emb = base + (size_t)1960 * nc;    // [N][64]

    for (int k = 0; k < c; ++k) {
        int n0 = k * nc;
        transpose_x<<<dim3(13, nc / 64), 256, 0, stream>>>(
            x + (size_t)n0 * 784, xt, nc);
        conv1_bt<<<196 * (nc / 512), 256, 0, stream>>>(
            xt, c1w, c1b, p1t, nc);
        conv2_bt<<<25 * (nc / 256), 256, 0, stream>>>(
            p1t, c2w, c2b, ht_, nc);
        lenet_fc_t<<<nc / 32, 256, 0, stream>>>(
            ht_, f1w, f1b, f2w, f2b, f3w, f3b, emb + (size_t)n0 * 64, nc);
    }
    proto_head<<<(N + 3) / 4, 256, 0, stream>>>(emb, out, N);
}

// Round 4
// 324.335 us; speedup vs baseline: 1.8063x; 1.0620x over previous
//
#include <hip/hip_runtime.h>

// ---------------------------------------------------------------------------
// Batch-inner LeNet: lane = image, activations in [feature][N] layout.
// Conv weights are wave-uniform -> scalar loads (s_load, SGPR operands),
// zero LDS in conv kernels. XCD swizzle keeps an image-group's activations
// resident in one XCD's L2.
// ---------------------------------------------------------------------------

__device__ __forceinline__ int xcd_swizzle(int orig, int nwg) {
    // m204 bijective: xcd = orig%8 gets a contiguous newid range.
    int xcd = orig & 7, q = nwg >> 3, r = nwg & 7;
    int base = (xcd < r) ? xcd * (q + 1) : r * (q + 1) + (xcd - r) * q;
    return base + (orig >> 3);
}

// Transpose x[nc,784] -> xt[1024,nc] (zero-padded 32x32 image layout).
// grid = (16, nc/64).
__global__ __launch_bounds__(256) void transpose_x(
    const float* __restrict__ x, float* __restrict__ xt, int nc)
{
    __shared__ float t[64][65];
    const int tx = threadIdx.x & 63, ty = threadIdx.x >> 6;  // ty 0..3
    const int p0 = blockIdx.x * 64, n0 = blockIdx.y * 64;
    #pragma unroll
    for (int rr = 0; rr < 16; ++rr) {
        int nl = rr * 4 + ty;
        int pp = p0 + tx;              // padded pixel 0..1023
        int pr = pp >> 5, pc = pp & 31;
        float v = 0.f;
        if (pr >= 2 && pr < 30 && pc >= 2 && pc < 30)
            v = x[(size_t)(n0 + nl) * 784 + (pr - 2) * 28 + (pc - 2)];
        t[tx][nl] = v;
    }
    __syncthreads();
    #pragma unroll
    for (int rr = 0; rr < 16; ++rr) {
        int pl = rr * 4 + ty;
        xt[(size_t)(p0 + pl) * nc + n0 + tx] = t[pl][tx];
    }
}

// conv1(pad2)+relu+pool. Flat grid = 196*(nc/512); 2 images per thread.
// Padded xt -> unconditional loads; weights via scalar pipe.
__global__ __launch_bounds__(256, 4) void conv1_bt(
    const float* __restrict__ xt, const float* __restrict__ c1w,
    const float* __restrict__ c1b, float* __restrict__ p1t, int nc)
{
    const int newid = xcd_swizzle(blockIdx.x, gridDim.x);
    const int grp = newid / 196, pos = newid - grp * 196;
    const int py = pos / 14, px = pos - py * 14;
    const int ia = grp * 512 + threadIdx.x;  // image A
    const int ib = ia + 256;                 // image B
    const int pbase = (2 * py) * 32 + 2 * px; // top-left of 6x6 in padded img

    float pa[36], pb[36];
    #pragma unroll
    for (int r = 0; r < 6; ++r)
        #pragma unroll
        for (int cc = 0; cc < 6; ++cc) {
            const float* p = &xt[(size_t)(pbase + r * 32 + cc) * nc];
            pa[r * 6 + cc] = p[ia];
            pb[r * 6 + cc] = p[ib];
        }

    #pragma unroll
    for (int ch = 0; ch < 6; ++ch) {
        float w[25];
        const float* wp = c1w + ch * 25;     // uniform -> s_load
        #pragma unroll
        for (int k = 0; k < 25; ++k) w[k] = wp[k];
        float b = c1b[ch];
        float ma = -1e30f, mb = -1e30f;
        #pragma unroll
        for (int dy = 0; dy < 2; ++dy)
        #pragma unroll
        for (int dx = 0; dx < 2; ++dx) {
            float aa = b, ab = b;
            #pragma unroll
            for (int ky = 0; ky < 5; ++ky)
            #pragma unroll
            for (int kx = 0; kx < 5; ++kx) {
                float ww = w[ky * 5 + kx];
                aa += pa[(dy + ky) * 6 + dx + kx] * ww;
                ab += pb[(dy + ky) * 6 + dx + kx] * ww;
            }
            ma = fmaxf(ma, aa); mb = fmaxf(mb, ab);
        }
        float* o = &p1t[(size_t)(ch * 196 + pos) * nc];
        o[ia] = fmaxf(ma, 0.f);
        o[ib] = fmaxf(mb, 0.f);
    }
}

// conv2(valid)+relu+pool, single pass: 1 image/thread, all 16 oc (acc[64]),
// patches loaded once per ci; weights via scalar pipe (zero LDS traffic).
// Flat grid = 25*(nc/256) with XCD swizzle. Feature order ch*25+qy*5+qx.
__global__ __launch_bounds__(256, 4) void conv2_bt(
    const float* __restrict__ p1t, const float* __restrict__ c2w,
    const float* __restrict__ c2b, float* __restrict__ ht, int nc)
{
    const int newid = xcd_swizzle(blockIdx.x, gridDim.x);
    const int grp = newid / 25, pos = newid - grp * 25;
    const int qy = pos / 5, qx = pos - qy * 5;
    const int img = grp * 256 + threadIdx.x;
    const int y0 = 2 * qy, x0 = 2 * qx;

    float acc[64];
    #pragma unroll
    for (int i = 0; i < 64; ++i) acc[i] = 0.f;

    #pragma unroll 1
    for (int ci = 0; ci < 6; ++ci) {
        float pa[36];
        #pragma unroll
        for (int r = 0; r < 6; ++r)
            #pragma unroll
            for (int cc = 0; cc < 6; ++cc)
                pa[r * 6 + cc] =
                    p1t[(size_t)(ci * 196 + (y0 + r) * 14 + x0 + cc) * nc + img];
        #pragma unroll
        for (int oc = 0; oc < 16; ++oc) {
            float w[25];
            const float* wp = c2w + (oc * 6 + ci) * 25;  // uniform -> s_load
            #pragma unroll
            for (int k = 0; k < 25; ++k) w[k] = wp[k];
            #pragma unroll
            for (int ky = 0; ky < 5; ++ky)
            #pragma unroll
            for (int kx = 0; kx < 5; ++kx) {
                float ww = w[ky * 5 + kx];
                acc[oc*4+0] += pa[ky*6+kx]       * ww;
                acc[oc*4+1] += pa[ky*6+kx+1]     * ww;
                acc[oc*4+2] += pa[(ky+1)*6+kx]   * ww;
                acc[oc*4+3] += pa[(ky+1)*6+kx+1] * ww;
            }
        }
    }
    #pragma unroll
    for (int oc = 0; oc < 16; ++oc) {
        float b = c2b[oc];
        float m = fmaxf(fmaxf(acc[oc*4+0], acc[oc*4+1]),
                        fmaxf(acc[oc*4+2], acc[oc*4+3])) + b;
        ht[(size_t)(oc * 25 + pos) * nc + img] = fmaxf(m, 0.f);
    }
}

// fc1+fc2+fc3 fused. Block = 32 images. fc1: h read direct from ht (L2,
// coalesced, VMEM pipe), weights via swizzled conflict-free ds_read_b128.
__global__ __launch_bounds__(256, 2) void lenet_fc_t(
    const float* __restrict__ ht,
    const float* __restrict__ f1w, const float* __restrict__ f1b,
    const float* __restrict__ f2w, const float* __restrict__ f2b,
    const float* __restrict__ f3w, const float* __restrict__ f3b,
    float* __restrict__ emb, int nc)
{
    __shared__ float wpool[6400];    // fc1: swizzled [50][128]; fc2/fc3 reuse
    __shared__ float a1[32 * 121];
    __shared__ float a2[32 * 85];

    const int tid = threadIdx.x;
    const int n0 = blockIdx.x * 32;
    const int ig = tid & 7;          // image group (4 rows each)
    const int og = tid >> 3;         // output group (4 outs each)

    float acc[16];
    #pragma unroll
    for (int j = 0; j < 16; ++j) acc[j] = 0.f;

    // ---- fc1: [32,400] @ [120,400]^T, K chunks of 50 ----
    for (int kc = 0; kc < 400; kc += 50) {
        __syncthreads();
        for (int i = tid; i < 6000; i += 256) {
            int r = i / 50, c = i - r * 50;          // r: out 0..119
            int rg = r >> 2, rl = r & 3;
            wpool[c * 128 + (((rg ^ (c & 7)) << 2) | rl)] = f1w[r * 400 + kc + c];
        }
        __syncthreads();
        if (og < 30) {
            #pragma unroll 2
            for (int kk = 0; kk < 50; ++kk) {
                const float* hp = &ht[(size_t)(kc + kk) * nc + n0 + ig * 4];
                float h0 = hp[0], h1 = hp[1], h2 = hp[2], h3 = hp[3];
                float4 wv = *(const float4*)&wpool[kk * 128 + ((og ^ (kk & 7)) << 2)];
                acc[0]  += h0 * wv.x; acc[1]  += h0 * wv.y;
                acc[2]  += h0 * wv.z; acc[3]  += h0 * wv.w;
                acc[4]  += h1 * wv.x; acc[5]  += h1 * wv.y;
                acc[6]  += h1 * wv.z; acc[7]  += h1 * wv.w;
                acc[8]  += h2 * wv.x; acc[9]  += h2 * wv.y;
                acc[10] += h2 * wv.z; acc[11] += h2 * wv.w;
                acc[12] += h3 * wv.x; acc[13] += h3 * wv.y;
                acc[14] += h3 * wv.z; acc[15] += h3 * wv.w;
            }
        }
    }
    __syncthreads();
    if (og < 30) {
        #pragma unroll
        for (int j = 0; j < 4; ++j) {
            int o = og * 4 + j;
            float bb = f1b[o];
            a1[(ig * 4 + 0) * 121 + o] = fmaxf(acc[j]      + bb, 0.f);
            a1[(ig * 4 + 1) * 121 + o] = fmaxf(acc[4 + j]  + bb, 0.f);
            a1[(ig * 4 + 2) * 121 + o] = fmaxf(acc[8 + j]  + bb, 0.f);
            a1[(ig * 4 + 3) * 121 + o] = fmaxf(acc[12 + j] + bb, 0.f);
        }
    }
    #pragma unroll
    for (int j = 0; j < 16; ++j) acc[j] = 0.f;

    // ---- fc2: [32,120] @ [84,120]^T, K chunks of 60, weights [84][61] ----
    for (int kc = 0; kc < 120; kc += 60) {
        __syncthreads();
        for (int i = tid; i < 84 * 60; i += 256) {
            int r = i / 60, c = i - r * 60;
            wpool[r * 61 + c] = f2w[r * 120 + kc + c];
        }
        __syncthreads();
        if (og < 21) {
            for (int kk = 0; kk < 60; ++kk) {
                float h0 = a1[(ig * 4 + 0) * 121 + kc + kk];
                float h1 = a1[(ig * 4 + 1) * 121 + kc + kk];
                float h2 = a1[(ig * 4 + 2) * 121 + kc + kk];
                float h3 = a1[(ig * 4 + 3) * 121 + kc + kk];
                #pragma unroll
                for (int j = 0; j < 4; ++j) {
                    float w = wpool[(og * 4 + j) * 61 + kk];
                    acc[j]      += h0 * w;
                    acc[4 + j]  += h1 * w;
                    acc[8 + j]  += h2 * w;
                    acc[12 + j] += h3 * w;
                }
            }
        }
    }
    __syncthreads();
    if (og < 21) {
        #pragma unroll
        for (int j = 0; j < 4; ++j) {
            int o = og * 4 + j;
            float bb = f2b[o];
            a2[(ig * 4 + 0) * 85 + o] = fmaxf(acc[j]      + bb, 0.f);
            a2[(ig * 4 + 1) * 85 + o] = fmaxf(acc[4 + j]  + bb, 0.f);
            a2[(ig * 4 + 2) * 85 + o] = fmaxf(acc[8 + j]  + bb, 0.f);
            a2[(ig * 4 + 3) * 85 + o] = fmaxf(acc[12 + j] + bb, 0.f);
        }
    }
    // stage f3w [64][84] -> [64][85]
    for (int i = tid; i < 64 * 84; i += 256) {
        int r = i / 84, c = i - r * 84;
        wpool[r * 85 + c] = f3w[i];
    }
    #pragma unroll
    for (int j = 0; j < 16; ++j) acc[j] = 0.f;
    __syncthreads();

    // ---- fc3: [32,84] @ [64,84]^T (no relu) ----
    if (og < 16) {
        for (int kk = 0; kk < 84; ++kk) {
            float h0 = a2[(ig * 4 + 0) * 85 + kk];
            float h1 = a2[(ig * 4 + 1) * 85 + kk];
            float h2 = a2[(ig * 4 + 2) * 85 + kk];
            float h3 = a2[(ig * 4 + 3) * 85 + kk];
            #pragma unroll
            for (int j = 0; j < 4; ++j) {
                float w = wpool[(og * 4 + j) * 85 + kk];
                acc[j]      += h0 * w;
                acc[4 + j]  += h1 * w;
                acc[8 + j]  += h2 * w;
                acc[12 + j] += h3 * w;
            }
        }
    }
    __syncthreads();                  // a1 now dead -> reuse as emb stage
    if (og < 16) {
        #pragma unroll
        for (int j = 0; j < 4; ++j) {
            int o = og * 4 + j;
            float bb = f3b[o];
            #pragma unroll
            for (int r = 0; r < 4; ++r)
                a1[(ig * 4 + r) * 67 + o] = acc[r * 4 + j] + bb;
        }
    }
    __syncthreads();
    for (int i = tid; i < 2048; i += 256) {
        int row = i >> 6, o = i & 63;
        emb[(size_t)(n0 + row) * 64 + o] = a1[row * 67 + o];
    }
}

// softmax(64) + |s - proto|, proto = emb[0]/5. One wave per row.
__global__ __launch_bounds__(256) void proto_head(
    const float* __restrict__ emb, float* __restrict__ out, int N)
{
    int row  = blockIdx.x * 4 + (threadIdx.x >> 6);
    int lane = threadIdx.x & 63;
    if (row >= N) return;
    float v = emb[(size_t)row * 64 + lane];
    float m = v;
    #pragma unroll
    for (int off = 32; off >= 1; off >>= 1)
        m = fmaxf(m, __shfl_xor(m, off));
    float e = expf(v - m);
    float s = e;
    #pragma unroll
    for (int off = 32; off >= 1; off >>= 1)
        s += __shfl_xor(s, off);
    float sm = e / s;
    float proto = emb[lane] * 0.2f;
    out[(size_t)row * 64 + lane] = fabsf(sm - proto);
}

extern "C" void kernel_launch(void* const* d_in, const int* in_sizes, int n_in,
                              void* d_out, int out_size, void* d_ws, size_t ws_size,
                              hipStream_t stream)
{
    const float* x   = (const float*)d_in[0];
    const float* c1w = (const float*)d_in[1];
    const float* c1b = (const float*)d_in[2];
    const float* c2w = (const float*)d_in[3];
    const float* c2b = (const float*)d_in[4];
    const float* f1w = (const float*)d_in[5];
    const float* f1b = (const float*)d_in[6];
    const float* f2w = (const float*)d_in[7];
    const float* f2b = (const float*)d_in[8];
    const float* f3w = (const float*)d_in[9];
    const float* f3b = (const float*)d_in[10];
    float* out = (float*)d_out;

    const int N = in_sizes[0] / 784;          // 20480
    float* base = (float*)d_ws;

    // per chunk floats: xt 1024nc (aliased later by ht 400nc) + p1t 1176nc
    // + emb 64N persistent  -> bytes = 8800nc + 256N
    int c = 40;
    const int cands[] = {1, 2, 4, 5, 8, 10, 20, 40};
    for (int k = 0; k < 8; ++k) {
        int cd = cands[k];
        if (N % cd) continue;
        int ncq = N / cd;
        if (ncq % 512) continue;
        size_t need = (size_t)8800 * ncq + (size_t)256 * N;
        if (need <= ws_size) { c = cd; break; }
    }
    const int nc = N / c;

    float* xt  = base;                        // [1024][nc] padded images
    float* p1t = base + (size_t)1024 * nc;    // [1176][nc]
    float* ht_ = base;                        // [400][nc], aliases xt (dead)
    float* emb = base + (size_t)2200 * nc;    // [N][64]

    for (int k = 0; k < c; ++k) {
        int n0 = k * nc;
        transpose_x<<<dim3(16, nc / 64), 256, 0, stream>>>(
            x + (size_t)n0 * 784, xt, nc);
        conv1_bt<<<196 * (nc / 512), 256, 0, stream>>>(
            xt, c1w, c1b, p1t, nc);
        conv2_bt<<<25 * (nc / 256), 256, 0, stream>>>(
            p1t, c2w, c2b, ht_, nc);
        lenet_fc_t<<<nc / 32, 256, 0, stream>>>(
            ht_, f1w, f1b, f2w, f2b, f3w, f3b, emb + (size_t)n0 * 64, nc);
    }
    proto_head<<<(N + 3) / 4, 256, 0, stream>>>(emb, out, N);
}

// Round 5
// 297.321 us; speedup vs baseline: 1.9704x; 1.0909x over previous
//
#include <hip/hip_runtime.h>

// ---------------------------------------------------------------------------
// Batch-inner LeNet: lane = image, activations in [feature][N] layout.
// All weights are wave-uniform -> scalar loads (s_load, SGPR operands);
// zero LDS outside the transpose. XCD swizzle keeps an image-group's
// activations resident in one XCD's L2.
// ---------------------------------------------------------------------------

__device__ __forceinline__ int xcd_swizzle(int orig, int nwg) {
    // m204 bijective: xcd = orig%8 gets a contiguous newid range.
    int xcd = orig & 7, q = nwg >> 3, r = nwg & 7;
    int base = (xcd < r) ? xcd * (q + 1) : r * (q + 1) + (xcd - r) * q;
    return base + (orig >> 3);
}

// Transpose x[nc,784] -> xt[1024,nc] (zero-padded 32x32 image layout).
// grid = (16, nc/64).
__global__ __launch_bounds__(256) void transpose_x(
    const float* __restrict__ x, float* __restrict__ xt, int nc)
{
    __shared__ float t[64][65];
    const int tx = threadIdx.x & 63, ty = threadIdx.x >> 6;  // ty 0..3
    const int p0 = blockIdx.x * 64, n0 = blockIdx.y * 64;
    #pragma unroll
    for (int rr = 0; rr < 16; ++rr) {
        int nl = rr * 4 + ty;
        int pp = p0 + tx;              // padded pixel 0..1023
        int pr = pp >> 5, pc = pp & 31;
        float v = 0.f;
        if (pr >= 2 && pr < 30 && pc >= 2 && pc < 30)
            v = x[(size_t)(n0 + nl) * 784 + (pr - 2) * 28 + (pc - 2)];
        t[tx][nl] = v;
    }
    __syncthreads();
    #pragma unroll
    for (int rr = 0; rr < 16; ++rr) {
        int pl = rr * 4 + ty;
        xt[(size_t)(p0 + pl) * nc + n0 + tx] = t[pl][tx];
    }
}

// conv1(pad2)+relu+pool. Flat grid = 196*(nc/512); 2 consecutive images per
// thread via float2. Weights via scalar pipe. ~90 VGPR, no spill.
__global__ __launch_bounds__(256, 2) void conv1_bt(
    const float* __restrict__ xt, const float* __restrict__ c1w,
    const float* __restrict__ c1b, float* __restrict__ p1t, int nc)
{
    const int newid = xcd_swizzle(blockIdx.x, gridDim.x);
    const int grp = newid / 196, pos = newid - grp * 196;
    const int py = pos / 14, px = pos - py * 14;
    const int img = grp * 512 + threadIdx.x * 2;
    const int pbase = (2 * py) * 32 + 2 * px; // top-left of 6x6 in padded img

    float2 p[36];
    #pragma unroll
    for (int r = 0; r < 6; ++r)
        #pragma unroll
        for (int cc = 0; cc < 6; ++cc)
            p[r * 6 + cc] =
                *(const float2*)&xt[(size_t)(pbase + r * 32 + cc) * nc + img];

    #pragma unroll
    for (int ch = 0; ch < 6; ++ch) {
        float w[25];
        const float* wp = c1w + ch * 25;     // uniform -> s_load
        #pragma unroll
        for (int k = 0; k < 25; ++k) w[k] = wp[k];
        float b = c1b[ch];
        float ma = -1e30f, mb = -1e30f;
        #pragma unroll
        for (int dy = 0; dy < 2; ++dy)
        #pragma unroll
        for (int dx = 0; dx < 2; ++dx) {
            float aa = b, ab = b;
            #pragma unroll
            for (int ky = 0; ky < 5; ++ky)
            #pragma unroll
            for (int kx = 0; kx < 5; ++kx) {
                float ww = w[ky * 5 + kx];
                float2 pv = p[(dy + ky) * 6 + dx + kx];
                aa += pv.x * ww;
                ab += pv.y * ww;
            }
            ma = fmaxf(ma, aa); mb = fmaxf(mb, ab);
        }
        float2 o2 = make_float2(fmaxf(ma, 0.f), fmaxf(mb, 0.f));
        *(float2*)&p1t[(size_t)(ch * 196 + pos) * nc + img] = o2;
    }
}

// conv2(valid)+relu+pool: 1 image/thread, 2 passes of 8 oc (acc[32]+pa[36]
// ~80 VGPR, spill-free). Weights via scalar pipe. Flat grid = 25*(nc/256).
// Feature order ch*25 + qy*5 + qx matches reference flatten.
__global__ __launch_bounds__(256, 2) void conv2_bt(
    const float* __restrict__ p1t, const float* __restrict__ c2w,
    const float* __restrict__ c2b, float* __restrict__ ht, int nc)
{
    const int newid = xcd_swizzle(blockIdx.x, gridDim.x);
    const int grp = newid / 25, pos = newid - grp * 25;
    const int qy = pos / 5, qx = pos - qy * 5;
    const int img = grp * 256 + threadIdx.x;
    const int y0 = 2 * qy, x0 = 2 * qx;

    #pragma unroll 1
    for (int pass = 0; pass < 2; ++pass) {
        float acc[32];
        #pragma unroll
        for (int i = 0; i < 32; ++i) acc[i] = 0.f;

        #pragma unroll 1
        for (int ci = 0; ci < 6; ++ci) {
            float pa[36];
            #pragma unroll
            for (int r = 0; r < 6; ++r)
                #pragma unroll
                for (int cc = 0; cc < 6; ++cc)
                    pa[r * 6 + cc] =
                        p1t[(size_t)(ci * 196 + (y0 + r) * 14 + x0 + cc) * nc + img];
            #pragma unroll
            for (int o8 = 0; o8 < 8; ++o8) {
                float w[25];
                const float* wp = c2w + ((pass * 8 + o8) * 6 + ci) * 25;
                #pragma unroll
                for (int k = 0; k < 25; ++k) w[k] = wp[k];
                #pragma unroll
                for (int ky = 0; ky < 5; ++ky)
                #pragma unroll
                for (int kx = 0; kx < 5; ++kx) {
                    float ww = w[ky * 5 + kx];
                    acc[o8*4+0] += pa[ky*6+kx]       * ww;
                    acc[o8*4+1] += pa[ky*6+kx+1]     * ww;
                    acc[o8*4+2] += pa[(ky+1)*6+kx]   * ww;
                    acc[o8*4+3] += pa[(ky+1)*6+kx+1] * ww;
                }
            }
        }
        #pragma unroll
        for (int o8 = 0; o8 < 8; ++o8) {
            int oc = pass * 8 + o8;
            float b = c2b[oc];
            float m = fmaxf(fmaxf(acc[o8*4+0], acc[o8*4+1]),
                            fmaxf(acc[o8*4+2], acc[o8*4+3])) + b;
            ht[(size_t)(oc * 25 + pos) * nc + img] = fmaxf(m, 0.f);
        }
    }
}

// fc1: a1t[o][n] = relu(sum_k ht[k][n]*f1w[o][k] + b). 2 img/thread (float2),
// 8 outs/block-group. Flat grid = 15*(nc/512), XCD-swizzled.
__global__ __launch_bounds__(256) void fc1_bt(
    const float* __restrict__ ht, const float* __restrict__ f1w,
    const float* __restrict__ f1b, float* __restrict__ a1t, int nc)
{
    const int newid = xcd_swizzle(blockIdx.x, gridDim.x);
    const int grp = newid / 15, og = newid - grp * 15;
    const int img = grp * 512 + threadIdx.x * 2;
    const float* wb = f1w + og * 8 * 400;

    float2 acc[8];
    #pragma unroll
    for (int j = 0; j < 8; ++j) acc[j] = make_float2(0.f, 0.f);

    #pragma unroll 4
    for (int k = 0; k < 400; ++k) {
        float2 hv = *(const float2*)&ht[(size_t)k * nc + img];
        #pragma unroll
        for (int j = 0; j < 8; ++j) {
            float w = wb[j * 400 + k];        // uniform -> s_load
            acc[j].x += hv.x * w;
            acc[j].y += hv.y * w;
        }
    }
    #pragma unroll
    for (int j = 0; j < 8; ++j) {
        int o = og * 8 + j;
        float b = f1b[o];
        float2 o2 = make_float2(fmaxf(acc[j].x + b, 0.f),
                                fmaxf(acc[j].y + b, 0.f));
        *(float2*)&a1t[(size_t)o * nc + img] = o2;
    }
}

// fc2: a2t[o][n] = relu(sum_k a1t[k][n]*f2w[o][k] + b). 7 outs x 12 groups.
__global__ __launch_bounds__(256) void fc2_bt(
    const float* __restrict__ a1t, const float* __restrict__ f2w,
    const float* __restrict__ f2b, float* __restrict__ a2t, int nc)
{
    const int newid = xcd_swizzle(blockIdx.x, gridDim.x);
    const int grp = newid / 12, og = newid - grp * 12;
    const int img = grp * 512 + threadIdx.x * 2;
    const float* wb = f2w + og * 7 * 120;

    float2 acc[7];
    #pragma unroll
    for (int j = 0; j < 7; ++j) acc[j] = make_float2(0.f, 0.f);

    #pragma unroll 4
    for (int k = 0; k < 120; ++k) {
        float2 hv = *(const float2*)&a1t[(size_t)k * nc + img];
        #pragma unroll
        for (int j = 0; j < 7; ++j) {
            float w = wb[j * 120 + k];
            acc[j].x += hv.x * w;
            acc[j].y += hv.y * w;
        }
    }
    #pragma unroll
    for (int j = 0; j < 7; ++j) {
        int o = og * 7 + j;
        float b = f2b[o];
        float2 o2 = make_float2(fmaxf(acc[j].x + b, 0.f),
                                fmaxf(acc[j].y + b, 0.f));
        *(float2*)&a2t[(size_t)o * nc + img] = o2;
    }
}

// fc3 (no relu): embt[o][n0+n] = sum_k a2t[k][n]*f3w[o][k] + b.
// embt is the FULL-N buffer [64][Ntot]; chunk writes at offset n0.
__global__ __launch_bounds__(256) void fc3_bt(
    const float* __restrict__ a2t, const float* __restrict__ f3w,
    const float* __restrict__ f3b, float* __restrict__ embt,
    int nc, int Ntot, int n0)
{
    const int newid = xcd_swizzle(blockIdx.x, gridDim.x);
    const int grp = newid / 8, og = newid - grp * 8;
    const int limg = grp * 512 + threadIdx.x * 2;
    const float* wb = f3w + og * 8 * 84;

    float2 acc[8];
    #pragma unroll
    for (int j = 0; j < 8; ++j) acc[j] = make_float2(0.f, 0.f);

    #pragma unroll 4
    for (int k = 0; k < 84; ++k) {
        float2 hv = *(const float2*)&a2t[(size_t)k * nc + limg];
        #pragma unroll
        for (int j = 0; j < 8; ++j) {
            float w = wb[j * 84 + k];
            acc[j].x += hv.x * w;
            acc[j].y += hv.y * w;
        }
    }
    #pragma unroll
    for (int j = 0; j < 8; ++j) {
        int o = og * 8 + j;
        float b = f3b[o];
        float2 o2 = make_float2(acc[j].x + b, acc[j].y + b);
        *(float2*)&embt[(size_t)o * Ntot + n0 + limg] = o2;
    }
}

// Head: thread = image. Serial 64-wide softmax in registers; proto via
// uniform s_load of embt[o][0]. Stores 64 consecutive floats per thread.
__global__ __launch_bounds__(256) void proto_head_t(
    const float* __restrict__ embt, float* __restrict__ out, int N)
{
    const int img = blockIdx.x * 256 + threadIdx.x;
    float v[64];
    float m = -1e30f;
    #pragma unroll
    for (int o = 0; o < 64; ++o) {
        v[o] = embt[(size_t)o * N + img];
        m = fmaxf(m, v[o]);
    }
    float s = 0.f;
    #pragma unroll
    for (int o = 0; o < 64; ++o) {
        v[o] = __expf(v[o] - m);
        s += v[o];
    }
    float inv = __frcp_rn(s);
    #pragma unroll
    for (int o = 0; o < 64; o += 4) {
        float4 r;
        r.x = fabsf(v[o+0] * inv - embt[(size_t)(o+0) * N] * 0.2f);
        r.y = fabsf(v[o+1] * inv - embt[(size_t)(o+1) * N] * 0.2f);
        r.z = fabsf(v[o+2] * inv - embt[(size_t)(o+2) * N] * 0.2f);
        r.w = fabsf(v[o+3] * inv - embt[(size_t)(o+3) * N] * 0.2f);
        *(float4*)&out[(size_t)img * 64 + o] = r;
    }
}

extern "C" void kernel_launch(void* const* d_in, const int* in_sizes, int n_in,
                              void* d_out, int out_size, void* d_ws, size_t ws_size,
                              hipStream_t stream)
{
    const float* x   = (const float*)d_in[0];
    const float* c1w = (const float*)d_in[1];
    const float* c1b = (const float*)d_in[2];
    const float* c2w = (const float*)d_in[3];
    const float* c2b = (const float*)d_in[4];
    const float* f1w = (const float*)d_in[5];
    const float* f1b = (const float*)d_in[6];
    const float* f2w = (const float*)d_in[7];
    const float* f2b = (const float*)d_in[8];
    const float* f3w = (const float*)d_in[9];
    const float* f3b = (const float*)d_in[10];
    float* out = (float*)d_out;

    const int N = in_sizes[0] / 784;          // 20480
    float* base = (float*)d_ws;

    // Region A: xt[1024][nc] -> reused as ht[400][nc]
    // Region B: p1t[1176][nc] -> reused as a1t[120][nc] + a2t[84][nc]
    // embt[64][N] persistent.  bytes = 8800nc + 256N
    int c = 40;
    const int cands[] = {1, 2, 4, 5, 8, 10, 20, 40};
    for (int k = 0; k < 8; ++k) {
        int cd = cands[k];
        if (N % cd) continue;
        int ncq = N / cd;
        if (ncq % 512) continue;
        size_t need = (size_t)8800 * ncq + (size_t)256 * N;
        if (need <= ws_size) { c = cd; break; }
    }
    const int nc = N / c;

    float* xt   = base;                        // [1024][nc] padded images
    float* p1t  = base + (size_t)1024 * nc;    // [1176][nc]
    float* ht_  = base;                        // [400][nc]  (over xt)
    float* a1t  = p1t;                         // [120][nc]  (over p1t)
    float* a2t  = p1t + (size_t)120 * nc;      // [84][nc]
    float* embt = base + (size_t)2200 * nc;    // [64][N]

    for (int k = 0; k < c; ++k) {
        int n0 = k * nc;
        transpose_x<<<dim3(16, nc / 64), 256, 0, stream>>>(
            x + (size_t)n0 * 784, xt, nc);
        conv1_bt<<<196 * (nc / 512), 256, 0, stream>>>(
            xt, c1w, c1b, p1t, nc);
        conv2_bt<<<25 * (nc / 256), 256, 0, stream>>>(
            p1t, c2w, c2b, ht_, nc);
        fc1_bt<<<15 * (nc / 512), 256, 0, stream>>>(
            ht_, f1w, f1b, a1t, nc);
        fc2_bt<<<12 * (nc / 512), 256, 0, stream>>>(
            a1t, f2w, f2b, a2t, nc);
        fc3_bt<<<8 * (nc / 512), 256, 0, stream>>>(
            a2t, f3w, f3b, embt, nc, N, n0);
    }
    proto_head_t<<<N / 256, 256, 0, stream>>>(embt, out, N);
}

// Round 6
// 290.283 us; speedup vs baseline: 2.0182x; 1.0242x over previous
//
#include <hip/hip_runtime.h>

// ---------------------------------------------------------------------------
// Batch-inner LeNet: lane = image, activations in [feature][N] layout.
// All weights are wave-uniform -> scalar loads (s_load, SGPR operands);
// zero LDS outside the transpose. XCD swizzle keeps an image-group's
// activations resident in one XCD's L2.
// ---------------------------------------------------------------------------

__device__ __forceinline__ int xcd_swizzle(int orig, int nwg) {
    // m204 bijective: xcd = orig%8 gets a contiguous newid range.
    int xcd = orig & 7, q = nwg >> 3, r = nwg & 7;
    int base = (xcd < r) ? xcd * (q + 1) : r * (q + 1) + (xcd - r) * q;
    return base + (orig >> 3);
}

// Transpose x[nc,784] -> xt[1024,nc] (zero-padded 32x32 image layout).
// grid = (16, nc/64).
__global__ __launch_bounds__(256) void transpose_x(
    const float* __restrict__ x, float* __restrict__ xt, int nc)
{
    __shared__ float t[64][65];
    const int tx = threadIdx.x & 63, ty = threadIdx.x >> 6;  // ty 0..3
    const int p0 = blockIdx.x * 64, n0 = blockIdx.y * 64;
    #pragma unroll
    for (int rr = 0; rr < 16; ++rr) {
        int nl = rr * 4 + ty;
        int pp = p0 + tx;              // padded pixel 0..1023
        int pr = pp >> 5, pc = pp & 31;
        float v = 0.f;
        if (pr >= 2 && pr < 30 && pc >= 2 && pc < 30)
            v = x[(size_t)(n0 + nl) * 784 + (pr - 2) * 28 + (pc - 2)];
        t[tx][nl] = v;
    }
    __syncthreads();
    #pragma unroll
    for (int rr = 0; rr < 16; ++rr) {
        int pl = rr * 4 + ty;
        xt[(size_t)(p0 + pl) * nc + n0 + tx] = t[pl][tx];
    }
}

// conv1(pad2)+relu+pool. Flat grid = 196*(nc/512); 2 consecutive images per
// thread via float2. Weights via scalar pipe. launch_bounds(256,1): allocator
// free up to 512 VGPR -> keep float2 patch (72 regs) resident, no remat.
__global__ __launch_bounds__(256, 1) void conv1_bt(
    const float* __restrict__ xt, const float* __restrict__ c1w,
    const float* __restrict__ c1b, float* __restrict__ p1t, int nc)
{
    const int newid = xcd_swizzle(blockIdx.x, gridDim.x);
    const int grp = newid / 196, pos = newid - grp * 196;
    const int py = pos / 14, px = pos - py * 14;
    const int img = grp * 512 + threadIdx.x * 2;
    const int pbase = (2 * py) * 32 + 2 * px; // top-left of 6x6 in padded img

    float2 p[36];
    #pragma unroll
    for (int r = 0; r < 6; ++r)
        #pragma unroll
        for (int cc = 0; cc < 6; ++cc)
            p[r * 6 + cc] =
                *(const float2*)&xt[(size_t)(pbase + r * 32 + cc) * nc + img];

    #pragma unroll
    for (int ch = 0; ch < 6; ++ch) {
        float w[25];
        const float* wp = c1w + ch * 25;     // uniform -> s_load
        #pragma unroll
        for (int k = 0; k < 25; ++k) w[k] = wp[k];
        float b = c1b[ch];
        float ma = -1e30f, mb = -1e30f;
        #pragma unroll
        for (int dy = 0; dy < 2; ++dy)
        #pragma unroll
        for (int dx = 0; dx < 2; ++dx) {
            float aa = b, ab = b;
            #pragma unroll
            for (int ky = 0; ky < 5; ++ky)
            #pragma unroll
            for (int kx = 0; kx < 5; ++kx) {
                float ww = w[ky * 5 + kx];
                float2 pv = p[(dy + ky) * 6 + dx + kx];
                aa += pv.x * ww;
                ab += pv.y * ww;
            }
            ma = fmaxf(ma, aa); mb = fmaxf(mb, ab);
        }
        float2 o2 = make_float2(fmaxf(ma, 0.f), fmaxf(mb, 0.f));
        *(float2*)&p1t[(size_t)(ch * 196 + pos) * nc + img] = o2;
    }
}

// conv2(valid)+relu+pool: 1 image/thread, 2 passes of 8 oc. acc[32]+pa[36]
// must stay register-resident: launch_bounds(256,1) lifts the VGPR cap so
// the allocator doesn't rematerialize patch loads (R5: VGPR=60 -> remat).
// Weights via scalar pipe. Flat grid = 25*(nc/256). Feature order
// ch*25 + qy*5 + qx matches reference flatten.
__global__ __launch_bounds__(256, 1) void conv2_bt(
    const float* __restrict__ p1t, const float* __restrict__ c2w,
    const float* __restrict__ c2b, float* __restrict__ ht, int nc)
{
    const int newid = xcd_swizzle(blockIdx.x, gridDim.x);
    const int grp = newid / 25, pos = newid - grp * 25;
    const int qy = pos / 5, qx = pos - qy * 5;
    const int img = grp * 256 + threadIdx.x;
    const int y0 = 2 * qy, x0 = 2 * qx;

    #pragma unroll 1
    for (int pass = 0; pass < 2; ++pass) {
        float acc[32];
        #pragma unroll
        for (int i = 0; i < 32; ++i) acc[i] = 0.f;

        #pragma unroll 1
        for (int ci = 0; ci < 6; ++ci) {
            float pa[36];
            #pragma unroll
            for (int r = 0; r < 6; ++r)
                #pragma unroll
                for (int cc = 0; cc < 6; ++cc)
                    pa[r * 6 + cc] =
                        p1t[(size_t)(ci * 196 + (y0 + r) * 14 + x0 + cc) * nc + img];
            #pragma unroll
            for (int o8 = 0; o8 < 8; ++o8) {
                float w[25];
                const float* wp = c2w + ((pass * 8 + o8) * 6 + ci) * 25;
                #pragma unroll
                for (int k = 0; k < 25; ++k) w[k] = wp[k];
                #pragma unroll
                for (int ky = 0; ky < 5; ++ky)
                #pragma unroll
                for (int kx = 0; kx < 5; ++kx) {
                    float ww = w[ky * 5 + kx];
                    acc[o8*4+0] += pa[ky*6+kx]       * ww;
                    acc[o8*4+1] += pa[ky*6+kx+1]     * ww;
                    acc[o8*4+2] += pa[(ky+1)*6+kx]   * ww;
                    acc[o8*4+3] += pa[(ky+1)*6+kx+1] * ww;
                }
            }
        }
        #pragma unroll
        for (int o8 = 0; o8 < 8; ++o8) {
            int oc = pass * 8 + o8;
            float b = c2b[oc];
            float m = fmaxf(fmaxf(acc[o8*4+0], acc[o8*4+1]),
                            fmaxf(acc[o8*4+2], acc[o8*4+3])) + b;
            ht[(size_t)(oc * 25 + pos) * nc + img] = fmaxf(m, 0.f);
        }
    }
}

// fc1: a1t[o][n] = relu(sum_k ht[k][n]*f1w[o][k] + b). 2 img/thread (float2),
// 8 outs/block-group. Flat grid = 15*(nc/512), XCD-swizzled.
__global__ __launch_bounds__(256) void fc1_bt(
    const float* __restrict__ ht, const float* __restrict__ f1w,
    const float* __restrict__ f1b, float* __restrict__ a1t, int nc)
{
    const int newid = xcd_swizzle(blockIdx.x, gridDim.x);
    const int grp = newid / 15, og = newid - grp * 15;
    const int img = grp * 512 + threadIdx.x * 2;
    const float* wb = f1w + og * 8 * 400;

    float2 acc[8];
    #pragma unroll
    for (int j = 0; j < 8; ++j) acc[j] = make_float2(0.f, 0.f);

    #pragma unroll 4
    for (int k = 0; k < 400; ++k) {
        float2 hv = *(const float2*)&ht[(size_t)k * nc + img];
        #pragma unroll
        for (int j = 0; j < 8; ++j) {
            float w = wb[j * 400 + k];        // uniform -> s_load
            acc[j].x += hv.x * w;
            acc[j].y += hv.y * w;
        }
    }
    #pragma unroll
    for (int j = 0; j < 8; ++j) {
        int o = og * 8 + j;
        float b = f1b[o];
        float2 o2 = make_float2(fmaxf(acc[j].x + b, 0.f),
                                fmaxf(acc[j].y + b, 0.f));
        *(float2*)&a1t[(size_t)o * nc + img] = o2;
    }
}

// fc2: a2t[o][n] = relu(sum_k a1t[k][n]*f2w[o][k] + b). 7 outs x 12 groups.
__global__ __launch_bounds__(256) void fc2_bt(
    const float* __restrict__ a1t, const float* __restrict__ f2w,
    const float* __restrict__ f2b, float* __restrict__ a2t, int nc)
{
    const int newid = xcd_swizzle(blockIdx.x, gridDim.x);
    const int grp = newid / 12, og = newid - grp * 12;
    const int img = grp * 512 + threadIdx.x * 2;
    const float* wb = f2w + og * 7 * 120;

    float2 acc[7];
    #pragma unroll
    for (int j = 0; j < 7; ++j) acc[j] = make_float2(0.f, 0.f);

    #pragma unroll 4
    for (int k = 0; k < 120; ++k) {
        float2 hv = *(const float2*)&a1t[(size_t)k * nc + img];
        #pragma unroll
        for (int j = 0; j < 7; ++j) {
            float w = wb[j * 120 + k];
            acc[j].x += hv.x * w;
            acc[j].y += hv.y * w;
        }
    }
    #pragma unroll
    for (int j = 0; j < 7; ++j) {
        int o = og * 7 + j;
        float b = f2b[o];
        float2 o2 = make_float2(fmaxf(acc[j].x + b, 0.f),
                                fmaxf(acc[j].y + b, 0.f));
        *(float2*)&a2t[(size_t)o * nc + img] = o2;
    }
}

// fc3 (no relu): embt[o][n0+n] = sum_k a2t[k][n]*f3w[o][k] + b.
// embt is the FULL-N buffer [64][Ntot]; chunk writes at offset n0.
__global__ __launch_bounds__(256) void fc3_bt(
    const float* __restrict__ a2t, const float* __restrict__ f3w,
    const float* __restrict__ f3b, float* __restrict__ embt,
    int nc, int Ntot, int n0)
{
    const int newid = xcd_swizzle(blockIdx.x, gridDim.x);
    const int grp = newid / 8, og = newid - grp * 8;
    const int limg = grp * 512 + threadIdx.x * 2;
    const float* wb = f3w + og * 8 * 84;

    float2 acc[8];
    #pragma unroll
    for (int j = 0; j < 8; ++j) acc[j] = make_float2(0.f, 0.f);

    #pragma unroll 4
    for (int k = 0; k < 84; ++k) {
        float2 hv = *(const float2*)&a2t[(size_t)k * nc + limg];
        #pragma unroll
        for (int j = 0; j < 8; ++j) {
            float w = wb[j * 84 + k];
            acc[j].x += hv.x * w;
            acc[j].y += hv.y * w;
        }
    }
    #pragma unroll
    for (int j = 0; j < 8; ++j) {
        int o = og * 8 + j;
        float b = f3b[o];
        float2 o2 = make_float2(acc[j].x + b, acc[j].y + b);
        *(float2*)&embt[(size_t)o * Ntot + n0 + limg] = o2;
    }
}

// Head: thread = image. Serial 64-wide softmax in registers; proto via
// uniform s_load of embt[o][0]. Stores 64 consecutive floats per thread.
__global__ __launch_bounds__(256) void proto_head_t(
    const float* __restrict__ embt, float* __restrict__ out, int N)
{
    const int img = blockIdx.x * 256 + threadIdx.x;
    float v[64];
    float m = -1e30f;
    #pragma unroll
    for (int o = 0; o < 64; ++o) {
        v[o] = embt[(size_t)o * N + img];
        m = fmaxf(m, v[o]);
    }
    float s = 0.f;
    #pragma unroll
    for (int o = 0; o < 64; ++o) {
        v[o] = __expf(v[o] - m);
        s += v[o];
    }
    float inv = __frcp_rn(s);
    #pragma unroll
    for (int o = 0; o < 64; o += 4) {
        float4 r;
        r.x = fabsf(v[o+0] * inv - embt[(size_t)(o+0) * N] * 0.2f);
        r.y = fabsf(v[o+1] * inv - embt[(size_t)(o+1) * N] * 0.2f);
        r.z = fabsf(v[o+2] * inv - embt[(size_t)(o+2) * N] * 0.2f);
        r.w = fabsf(v[o+3] * inv - embt[(size_t)(o+3) * N] * 0.2f);
        *(float4*)&out[(size_t)img * 64 + o] = r;
    }
}

extern "C" void kernel_launch(void* const* d_in, const int* in_sizes, int n_in,
                              void* d_out, int out_size, void* d_ws, size_t ws_size,
                              hipStream_t stream)
{
    const float* x   = (const float*)d_in[0];
    const float* c1w = (const float*)d_in[1];
    const float* c1b = (const float*)d_in[2];
    const float* c2w = (const float*)d_in[3];
    const float* c2b = (const float*)d_in[4];
    const float* f1w = (const float*)d_in[5];
    const float* f1b = (const float*)d_in[6];
    const float* f2w = (const float*)d_in[7];
    const float* f2b = (const float*)d_in[8];
    const float* f3w = (const float*)d_in[9];
    const float* f3b = (const float*)d_in[10];
    float* out = (float*)d_out;

    const int N = in_sizes[0] / 784;          // 20480
    float* base = (float*)d_ws;

    // Region A: xt[1024][nc] -> reused as ht[400][nc]
    // Region B: p1t[1176][nc] -> reused as a1t[120][nc] + a2t[84][nc]
    // embt[64][N] persistent.  bytes = 8800nc + 256N
    int c = 40;
    const int cands[] = {1, 2, 4, 5, 8, 10, 20, 40};
    for (int k = 0; k < 8; ++k) {
        int cd = cands[k];
        if (N % cd) continue;
        int ncq = N / cd;
        if (ncq % 512) continue;
        size_t need = (size_t)8800 * ncq + (size_t)256 * N;
        if (need <= ws_size) { c = cd; break; }
    }
    const int nc = N / c;

    float* xt   = base;                        // [1024][nc] padded images
    float* p1t  = base + (size_t)1024 * nc;    // [1176][nc]
    float* ht_  = base;                        // [400][nc]  (over xt)
    float* a1t  = p1t;                         // [120][nc]  (over p1t)
    float* a2t  = p1t + (size_t)120 * nc;      // [84][nc]
    float* embt = base + (size_t)2200 * nc;    // [64][N]

    for (int k = 0; k < c; ++k) {
        int n0 = k * nc;
        transpose_x<<<dim3(16, nc / 64), 256, 0, stream>>>(
            x + (size_t)n0 * 784, xt, nc);
        conv1_bt<<<196 * (nc / 512), 256, 0, stream>>>(
            xt, c1w, c1b, p1t, nc);
        conv2_bt<<<25 * (nc / 256), 256, 0, stream>>>(
            p1t, c2w, c2b, ht_, nc);
        fc1_bt<<<15 * (nc / 512), 256, 0, stream>>>(
            ht_, f1w, f1b, a1t, nc);
        fc2_bt<<<12 * (nc / 512), 256, 0, stream>>>(
            a1t, f2w, f2b, a2t, nc);
        fc3_bt<<<8 * (nc / 512), 256, 0, stream>>>(
            a2t, f3w, f3b, embt, nc, N, n0);
    }
    proto_head_t<<<N / 256, 256, 0, stream>>>(embt, out, N);
}

// Round 7
// 288.620 us; speedup vs baseline: 2.0298x; 1.0058x over previous
//
#include <hip/hip_runtime.h>

// ---------------------------------------------------------------------------
// Batch-inner LeNet: lane = image, activations in [feature][N] layout.
// All weights are wave-uniform -> scalar loads (s_load, SGPR operands);
// zero LDS outside the transpose. XCD swizzle keeps an image-group's
// activations resident in one XCD's L2.
// ---------------------------------------------------------------------------

__device__ __forceinline__ int xcd_swizzle(int orig, int nwg) {
    // m204 bijective: xcd = orig%8 gets a contiguous newid range.
    int xcd = orig & 7, q = nwg >> 3, r = nwg & 7;
    int base = (xcd < r) ? xcd * (q + 1) : r * (q + 1) + (xcd - r) * q;
    return base + (orig >> 3);
}

// Transpose x[nc,784] -> xt[1024,nc] (zero-padded 32x32 image layout).
// grid = (16, nc/64).
__global__ __launch_bounds__(256) void transpose_x(
    const float* __restrict__ x, float* __restrict__ xt, int nc)
{
    __shared__ float t[64][65];
    const int tx = threadIdx.x & 63, ty = threadIdx.x >> 6;  // ty 0..3
    const int p0 = blockIdx.x * 64, n0 = blockIdx.y * 64;
    #pragma unroll
    for (int rr = 0; rr < 16; ++rr) {
        int nl = rr * 4 + ty;
        int pp = p0 + tx;              // padded pixel 0..1023
        int pr = pp >> 5, pc = pp & 31;
        float v = 0.f;
        if (pr >= 2 && pr < 30 && pc >= 2 && pc < 30)
            v = x[(size_t)(n0 + nl) * 784 + (pr - 2) * 28 + (pc - 2)];
        t[tx][nl] = v;
    }
    __syncthreads();
    #pragma unroll
    for (int rr = 0; rr < 16; ++rr) {
        int pl = rr * 4 + ty;
        xt[(size_t)(p0 + pl) * nc + n0 + tx] = t[pl][tx];
    }
}

// conv1(pad2)+relu+pool. Flat grid = 196*(nc/512); 2 consecutive images per
// thread via float2. Weights via scalar pipe.
__global__ __launch_bounds__(256, 1) void conv1_bt(
    const float* __restrict__ xt, const float* __restrict__ c1w,
    const float* __restrict__ c1b, float* __restrict__ p1t, int nc)
{
    const int newid = xcd_swizzle(blockIdx.x, gridDim.x);
    const int grp = newid / 196, pos = newid - grp * 196;
    const int py = pos / 14, px = pos - py * 14;
    const int img = grp * 512 + threadIdx.x * 2;
    const int pbase = (2 * py) * 32 + 2 * px; // top-left of 6x6 in padded img

    float2 p[36];
    #pragma unroll
    for (int r = 0; r < 6; ++r)
        #pragma unroll
        for (int cc = 0; cc < 6; ++cc)
            p[r * 6 + cc] =
                *(const float2*)&xt[(size_t)(pbase + r * 32 + cc) * nc + img];

    #pragma unroll
    for (int ch = 0; ch < 6; ++ch) {
        float w[25];
        const float* wp = c1w + ch * 25;     // uniform -> s_load
        #pragma unroll
        for (int k = 0; k < 25; ++k) w[k] = wp[k];
        float b = c1b[ch];
        float ma = -1e30f, mb = -1e30f;
        #pragma unroll
        for (int dy = 0; dy < 2; ++dy)
        #pragma unroll
        for (int dx = 0; dx < 2; ++dx) {
            float aa = b, ab = b;
            #pragma unroll
            for (int ky = 0; ky < 5; ++ky)
            #pragma unroll
            for (int kx = 0; kx < 5; ++kx) {
                float ww = w[ky * 5 + kx];
                float2 pv = p[(dy + ky) * 6 + dx + kx];
                aa += pv.x * ww;
                ab += pv.y * ww;
            }
            ma = fmaxf(ma, aa); mb = fmaxf(mb, ab);
        }
        float2 o2 = make_float2(fmaxf(ma, 0.f), fmaxf(mb, 0.f));
        *(float2*)&p1t[(size_t)(ch * 196 + pos) * nc + img] = o2;
    }
}

// conv2(valid)+relu+pool: 2 images/thread (float2), 2 passes of 8 oc.
// acc(64 VGPR) + patch(72 VGPR) resident -> no remat; FMA:load = 44:1.
// Weights via scalar pipe. Flat grid = 25*(nc/512). Feature order
// ch*25 + qy*5 + qx matches reference flatten.
__global__ __launch_bounds__(256, 1) void conv2_bt(
    const float* __restrict__ p1t, const float* __restrict__ c2w,
    const float* __restrict__ c2b, float* __restrict__ ht, int nc)
{
    const int newid = xcd_swizzle(blockIdx.x, gridDim.x);
    const int grp = newid / 25, pos = newid - grp * 25;
    const int qy = pos / 5, qx = pos - qy * 5;
    const int img = grp * 512 + threadIdx.x * 2;
    const int y0 = 2 * qy, x0 = 2 * qx;

    #pragma unroll 1
    for (int pass = 0; pass < 2; ++pass) {
        float2 acc[32];                      // [o8][quad], 2 imgs packed
        #pragma unroll
        for (int i = 0; i < 32; ++i) acc[i] = make_float2(0.f, 0.f);

        #pragma unroll 1
        for (int ci = 0; ci < 6; ++ci) {
            float2 pa[36];
            #pragma unroll
            for (int r = 0; r < 6; ++r)
                #pragma unroll
                for (int cc = 0; cc < 6; ++cc)
                    pa[r * 6 + cc] = *(const float2*)
                        &p1t[(size_t)(ci * 196 + (y0 + r) * 14 + x0 + cc) * nc + img];
            #pragma unroll
            for (int o8 = 0; o8 < 8; ++o8) {
                float w[25];
                const float* wp = c2w + ((pass * 8 + o8) * 6 + ci) * 25;
                #pragma unroll
                for (int k = 0; k < 25; ++k) w[k] = wp[k];
                #pragma unroll
                for (int ky = 0; ky < 5; ++ky)
                #pragma unroll
                for (int kx = 0; kx < 5; ++kx) {
                    float ww = w[ky * 5 + kx];
                    float2 p00 = pa[ky*6+kx];
                    float2 p01 = pa[ky*6+kx+1];
                    float2 p10 = pa[(ky+1)*6+kx];
                    float2 p11 = pa[(ky+1)*6+kx+1];
                    acc[o8*4+0].x += p00.x * ww; acc[o8*4+0].y += p00.y * ww;
                    acc[o8*4+1].x += p01.x * ww; acc[o8*4+1].y += p01.y * ww;
                    acc[o8*4+2].x += p10.x * ww; acc[o8*4+2].y += p10.y * ww;
                    acc[o8*4+3].x += p11.x * ww; acc[o8*4+3].y += p11.y * ww;
                }
            }
        }
        #pragma unroll
        for (int o8 = 0; o8 < 8; ++o8) {
            int oc = pass * 8 + o8;
            float b = c2b[oc];
            float mx = fmaxf(fmaxf(acc[o8*4+0].x, acc[o8*4+1].x),
                             fmaxf(acc[o8*4+2].x, acc[o8*4+3].x)) + b;
            float my = fmaxf(fmaxf(acc[o8*4+0].y, acc[o8*4+1].y),
                             fmaxf(acc[o8*4+2].y, acc[o8*4+3].y)) + b;
            float2 o2 = make_float2(fmaxf(mx, 0.f), fmaxf(my, 0.f));
            *(float2*)&ht[(size_t)(oc * 25 + pos) * nc + img] = o2;
        }
    }
}

// fc1: a1t[o][n] = relu(sum_k ht[k][n]*f1w[o][k] + b). 2 img/thread (float2),
// 8 outs/block-group. Flat grid = 15*(nc/512), XCD-swizzled.
__global__ __launch_bounds__(256) void fc1_bt(
    const float* __restrict__ ht, const float* __restrict__ f1w,
    const float* __restrict__ f1b, float* __restrict__ a1t, int nc)
{
    const int newid = xcd_swizzle(blockIdx.x, gridDim.x);
    const int grp = newid / 15, og = newid - grp * 15;
    const int img = grp * 512 + threadIdx.x * 2;
    const float* wb = f1w + og * 8 * 400;

    float2 acc[8];
    #pragma unroll
    for (int j = 0; j < 8; ++j) acc[j] = make_float2(0.f, 0.f);

    #pragma unroll 4
    for (int k = 0; k < 400; ++k) {
        float2 hv = *(const float2*)&ht[(size_t)k * nc + img];
        #pragma unroll
        for (int j = 0; j < 8; ++j) {
            float w = wb[j * 400 + k];        // uniform -> s_load
            acc[j].x += hv.x * w;
            acc[j].y += hv.y * w;
        }
    }
    #pragma unroll
    for (int j = 0; j < 8; ++j) {
        int o = og * 8 + j;
        float b = f1b[o];
        float2 o2 = make_float2(fmaxf(acc[j].x + b, 0.f),
                                fmaxf(acc[j].y + b, 0.f));
        *(float2*)&a1t[(size_t)o * nc + img] = o2;
    }
}

// fc2: a2t[o][n] = relu(sum_k a1t[k][n]*f2w[o][k] + b). 7 outs x 12 groups.
__global__ __launch_bounds__(256) void fc2_bt(
    const float* __restrict__ a1t, const float* __restrict__ f2w,
    const float* __restrict__ f2b, float* __restrict__ a2t, int nc)
{
    const int newid = xcd_swizzle(blockIdx.x, gridDim.x);
    const int grp = newid / 12, og = newid - grp * 12;
    const int img = grp * 512 + threadIdx.x * 2;
    const float* wb = f2w + og * 7 * 120;

    float2 acc[7];
    #pragma unroll
    for (int j = 0; j < 7; ++j) acc[j] = make_float2(0.f, 0.f);

    #pragma unroll 4
    for (int k = 0; k < 120; ++k) {
        float2 hv = *(const float2*)&a1t[(size_t)k * nc + img];
        #pragma unroll
        for (int j = 0; j < 7; ++j) {
            float w = wb[j * 120 + k];
            acc[j].x += hv.x * w;
            acc[j].y += hv.y * w;
        }
    }
    #pragma unroll
    for (int j = 0; j < 7; ++j) {
        int o = og * 7 + j;
        float b = f2b[o];
        float2 o2 = make_float2(fmaxf(acc[j].x + b, 0.f),
                                fmaxf(acc[j].y + b, 0.f));
        *(float2*)&a2t[(size_t)o * nc + img] = o2;
    }
}

// fc3 (no relu): embt[o][n0+n] = sum_k a2t[k][n]*f3w[o][k] + b.
// embt is the FULL-N buffer [64][Ntot]; chunk writes at offset n0.
__global__ __launch_bounds__(256) void fc3_bt(
    const float* __restrict__ a2t, const float* __restrict__ f3w,
    const float* __restrict__ f3b, float* __restrict__ embt,
    int nc, int Ntot, int n0)
{
    const int newid = xcd_swizzle(blockIdx.x, gridDim.x);
    const int grp = newid / 8, og = newid - grp * 8;
    const int limg = grp * 512 + threadIdx.x * 2;
    const float* wb = f3w + og * 8 * 84;

    float2 acc[8];
    #pragma unroll
    for (int j = 0; j < 8; ++j) acc[j] = make_float2(0.f, 0.f);

    #pragma unroll 4
    for (int k = 0; k < 84; ++k) {
        float2 hv = *(const float2*)&a2t[(size_t)k * nc + limg];
        #pragma unroll
        for (int j = 0; j < 8; ++j) {
            float w = wb[j * 84 + k];
            acc[j].x += hv.x * w;
            acc[j].y += hv.y * w;
        }
    }
    #pragma unroll
    for (int j = 0; j < 8; ++j) {
        int o = og * 8 + j;
        float b = f3b[o];
        float2 o2 = make_float2(acc[j].x + b, acc[j].y + b);
        *(float2*)&embt[(size_t)o * Ntot + n0 + limg] = o2;
    }
}

// Head: thread = image. Serial 64-wide softmax in registers; proto via
// uniform s_load of embt[o][0]. Stores 64 consecutive floats per thread.
__global__ __launch_bounds__(256) void proto_head_t(
    const float* __restrict__ embt, float* __restrict__ out, int N)
{
    const int img = blockIdx.x * 256 + threadIdx.x;
    float v[64];
    float m = -1e30f;
    #pragma unroll
    for (int o = 0; o < 64; ++o) {
        v[o] = embt[(size_t)o * N + img];
        m = fmaxf(m, v[o]);
    }
    float s = 0.f;
    #pragma unroll
    for (int o = 0; o < 64; ++o) {
        v[o] = __expf(v[o] - m);
        s += v[o];
    }
    float inv = __frcp_rn(s);
    #pragma unroll
    for (int o = 0; o < 64; o += 4) {
        float4 r;
        r.x = fabsf(v[o+0] * inv - embt[(size_t)(o+0) * N] * 0.2f);
        r.y = fabsf(v[o+1] * inv - embt[(size_t)(o+1) * N] * 0.2f);
        r.z = fabsf(v[o+2] * inv - embt[(size_t)(o+2) * N] * 0.2f);
        r.w = fabsf(v[o+3] * inv - embt[(size_t)(o+3) * N] * 0.2f);
        *(float4*)&out[(size_t)img * 64 + o] = r;
    }
}

extern "C" void kernel_launch(void* const* d_in, const int* in_sizes, int n_in,
                              void* d_out, int out_size, void* d_ws, size_t ws_size,
                              hipStream_t stream)
{
    const float* x   = (const float*)d_in[0];
    const float* c1w = (const float*)d_in[1];
    const float* c1b = (const float*)d_in[2];
    const float* c2w = (const float*)d_in[3];
    const float* c2b = (const float*)d_in[4];
    const float* f1w = (const float*)d_in[5];
    const float* f1b = (const float*)d_in[6];
    const float* f2w = (const float*)d_in[7];
    const float* f2b = (const float*)d_in[8];
    const float* f3w = (const float*)d_in[9];
    const float* f3b = (const float*)d_in[10];
    float* out = (float*)d_out;

    const int N = in_sizes[0] / 784;          // 20480
    float* base = (float*)d_ws;

    // Region A: xt[1024][nc] -> reused as ht[400][nc]
    // Region B: p1t[1176][nc] -> reused as a1t[120][nc] + a2t[84][nc]
    // embt[64][N] persistent.  bytes = 8800nc + 256N
    int c = 40;
    const int cands[] = {1, 2, 4, 5, 8, 10, 20, 40};
    for (int k = 0; k < 8; ++k) {
        int cd = cands[k];
        if (N % cd) continue;
        int ncq = N / cd;
        if (ncq % 512) continue;
        size_t need = (size_t)8800 * ncq + (size_t)256 * N;
        if (need <= ws_size) { c = cd; break; }
    }
    const int nc = N / c;

    float* xt   = base;                        // [1024][nc] padded images
    float* p1t  = base + (size_t)1024 * nc;    // [1176][nc]
    float* ht_  = base;                        // [400][nc]  (over xt)
    float* a1t  = p1t;                         // [120][nc]  (over p1t)
    float* a2t  = p1t + (size_t)120 * nc;      // [84][nc]
    float* embt = base + (size_t)2200 * nc;    // [64][N]

    for (int k = 0; k < c; ++k) {
        int n0 = k * nc;
        transpose_x<<<dim3(16, nc / 64), 256, 0, stream>>>(
            x + (size_t)n0 * 784, xt, nc);
        conv1_bt<<<196 * (nc / 512), 256, 0, stream>>>(
            xt, c1w, c1b, p1t, nc);
        conv2_bt<<<25 * (nc / 512), 256, 0, stream>>>(
            p1t, c2w, c2b, ht_, nc);
        fc1_bt<<<15 * (nc / 512), 256, 0, stream>>>(
            ht_, f1w, f1b, a1t, nc);
        fc2_bt<<<12 * (nc / 512), 256, 0, stream>>>(
            a1t, f2w, f2b, a2t, nc);
        fc3_bt<<<8 * (nc / 512), 256, 0, stream>>>(
            a2t, f3w, f3b, embt, nc, N, n0);
    }
    proto_head_t<<<N / 256, 256, 0, stream>>>(embt, out, N);
}